// Round 1
// baseline (699.687 us; speedup 1.0000x reference)
//
#include <hip/hip_runtime.h>
#include <hip/hip_bf16.h>

#define N_NODES 50000
#define N_EDGES 800000
#define IN_CH 256
#define HID 256
#define OUT_CH 128
#define N_GRAPHS 64

// ---------------------------------------------------------------------------
// CSR build: histogram of dst, block-wide exclusive scan, slot fill.
// ---------------------------------------------------------------------------
__global__ __launch_bounds__(256) void count_kernel(const int* __restrict__ ei,
                                                    int* __restrict__ cnt) {
    int e = blockIdx.x * 256 + threadIdx.x;
    if (e < N_EDGES) atomicAdd(&cnt[ei[N_EDGES + e]], 1);
}

__global__ __launch_bounds__(1024) void scan_kernel(const int* __restrict__ cnt,
                                                    int* __restrict__ rowptr,
                                                    float* __restrict__ dinv,
                                                    float* __restrict__ invdeg) {
    __shared__ int tmp[1024];
    __shared__ int carry_s;
    int tid = threadIdx.x;
    if (tid == 0) carry_s = 0;
    __syncthreads();
    for (int base = 0; base < N_NODES; base += 1024) {
        int i = base + tid;
        int v = (i < N_NODES) ? cnt[i] : 0;
        int x = v;
        tmp[tid] = x;
        __syncthreads();
        for (int off = 1; off < 1024; off <<= 1) {
            int y = (tid >= off) ? tmp[tid - off] : 0;
            __syncthreads();
            x += y;
            tmp[tid] = x;
            __syncthreads();
        }
        int carry = carry_s;   // uniform read (post-barrier)
        if (i < N_NODES) {
            rowptr[i] = carry + x - v;             // exclusive prefix
            float d = (float)v + 1.0f;             // +1 self loop
            dinv[i] = rsqrtf(d);
            invdeg[i] = 1.0f / d;
        }
        __syncthreads();
        if (tid == 1023) carry_s = carry + x;
        __syncthreads();
    }
    if (tid == 0) rowptr[N_NODES] = carry_s;
}

__global__ __launch_bounds__(256) void fill_kernel(const int* __restrict__ ei,
                                                   const int* __restrict__ rowptr,
                                                   int* __restrict__ fillp,
                                                   int* __restrict__ col,
                                                   float* __restrict__ wv,
                                                   const float* __restrict__ dinv) {
    int e = blockIdx.x * 256 + threadIdx.x;
    if (e >= N_EDGES) return;
    int s = ei[e];
    int d = ei[N_EDGES + e];
    int p = rowptr[d] + atomicAdd(&fillp[d], 1);
    col[p] = s;
    wv[p] = dinv[s] * dinv[d];
}

// ---------------------------------------------------------------------------
// f32 tiled GEMM: C[M,N] = A[M,K] @ B[K,N], row-major. BM=BN=64, BK=16,
// 256 threads, 4x4 microtile, float4 LDS reads (16B-aligned, no pad needed:
// 2-way bank alias is free on gfx950).
// ---------------------------------------------------------------------------
#define BM 64
#define BN 64
#define BK 16
__global__ __launch_bounds__(256) void gemm_kernel(const float* __restrict__ A,
                                                   const float* __restrict__ B,
                                                   float* __restrict__ C,
                                                   int M, int N, int K) {
    __shared__ float As[BK][BM];   // transposed: As[k][m]
    __shared__ float Bs[BK][BN];
    int tid = threadIdx.x;
    int bm = blockIdx.x * BM;
    int bn = blockIdx.y * BN;
    int tr = (tid >> 4) << 2;      // 0..60 row offset
    int tc = (tid & 15) << 2;      // 0..60 col offset
    int la_r = tid >> 2;           // 0..63 A row
    int la_k = (tid & 3) << 2;     // 0,4,8,12 A k-vec
    int lb_k = tid >> 4;           // 0..15 B k
    int lb_n = (tid & 15) << 2;    // B col vec
    const bool a_in = (bm + la_r) < M;
    float acc[4][4] = {};
    for (int k0 = 0; k0 < K; k0 += BK) {
        float4 av = a_in ? *(const float4*)(A + (size_t)(bm + la_r) * K + k0 + la_k)
                         : make_float4(0.f, 0.f, 0.f, 0.f);
        float4 bv = *(const float4*)(B + (size_t)(k0 + lb_k) * N + bn + lb_n);
        __syncthreads();
        As[la_k + 0][la_r] = av.x;
        As[la_k + 1][la_r] = av.y;
        As[la_k + 2][la_r] = av.z;
        As[la_k + 3][la_r] = av.w;
        *(float4*)&Bs[lb_k][lb_n] = bv;
        __syncthreads();
#pragma unroll
        for (int k = 0; k < BK; k++) {
            float4 ar = *(const float4*)&As[k][tr];
            float4 br = *(const float4*)&Bs[k][tc];
            acc[0][0] += ar.x * br.x; acc[0][1] += ar.x * br.y;
            acc[0][2] += ar.x * br.z; acc[0][3] += ar.x * br.w;
            acc[1][0] += ar.y * br.x; acc[1][1] += ar.y * br.y;
            acc[1][2] += ar.y * br.z; acc[1][3] += ar.y * br.w;
            acc[2][0] += ar.z * br.x; acc[2][1] += ar.z * br.y;
            acc[2][2] += ar.z * br.z; acc[2][3] += ar.z * br.w;
            acc[3][0] += ar.w * br.x; acc[3][1] += ar.w * br.y;
            acc[3][2] += ar.w * br.z; acc[3][3] += ar.w * br.w;
        }
    }
#pragma unroll
    for (int i = 0; i < 4; i++) {
        int r = bm + tr + i;
        if (r < M) {
            float4 o = make_float4(acc[i][0], acc[i][1], acc[i][2], acc[i][3]);
            *(float4*)(C + (size_t)r * N + bn + tc) = o;
        }
    }
}

// ---------------------------------------------------------------------------
// GCN aggregation, 256 channels (conv1): one wave per node, lane = 4 ch.
// acc = h[i]*invdeg[i] + sum_nbr h[s]*w + bias, then ELU. Coalesced 1KB
// gathers (h is L3-resident).
// ---------------------------------------------------------------------------
__global__ __launch_bounds__(256) void agg1_kernel(const float* __restrict__ h,
                                                   const float* __restrict__ bias,
                                                   const int* __restrict__ rowptr,
                                                   const int* __restrict__ col,
                                                   const float* __restrict__ wv,
                                                   const float* __restrict__ invdeg,
                                                   float* __restrict__ out) {
    int node = blockIdx.x * 4 + (threadIdx.x >> 6);
    if (node >= N_NODES) return;
    int lane = threadIdx.x & 63;
    const float4* h4 = (const float4*)h;
    float id = invdeg[node];
    float4 self = h4[(size_t)node * 64 + lane];
    float4 acc = make_float4(self.x * id, self.y * id, self.z * id, self.w * id);
    int e0 = rowptr[node], e1 = rowptr[node + 1];
    for (int e = e0; e < e1; e++) {
        int s = col[e];
        float w = wv[e];
        float4 v = h4[(size_t)s * 64 + lane];
        acc.x += v.x * w; acc.y += v.y * w; acc.z += v.z * w; acc.w += v.w * w;
    }
    float4 bb = ((const float4*)bias)[lane];
    acc.x += bb.x; acc.y += bb.y; acc.z += bb.z; acc.w += bb.w;
    acc.x = acc.x > 0.f ? acc.x : expm1f(acc.x);
    acc.y = acc.y > 0.f ? acc.y : expm1f(acc.y);
    acc.z = acc.z > 0.f ? acc.z : expm1f(acc.z);
    acc.w = acc.w > 0.f ? acc.w : expm1f(acc.w);
    ((float4*)out)[(size_t)node * 64 + lane] = acc;
}

// 128 channels (conv2): one wave per node, lane = 2 ch. No activation.
__global__ __launch_bounds__(256) void agg2_kernel(const float* __restrict__ h,
                                                   const float* __restrict__ bias,
                                                   const int* __restrict__ rowptr,
                                                   const int* __restrict__ col,
                                                   const float* __restrict__ wv,
                                                   const float* __restrict__ invdeg,
                                                   float* __restrict__ out) {
    int node = blockIdx.x * 4 + (threadIdx.x >> 6);
    if (node >= N_NODES) return;
    int lane = threadIdx.x & 63;
    const float2* h2 = (const float2*)h;
    float id = invdeg[node];
    float2 self = h2[(size_t)node * 64 + lane];
    float2 acc = make_float2(self.x * id, self.y * id);
    int e0 = rowptr[node], e1 = rowptr[node + 1];
    for (int e = e0; e < e1; e++) {
        int s = col[e];
        float w = wv[e];
        float2 v = h2[(size_t)s * 64 + lane];
        acc.x += v.x * w; acc.y += v.y * w;
    }
    float2 bb = ((const float2*)bias)[lane];
    acc.x += bb.x; acc.y += bb.y;
    ((float2*)out)[(size_t)node * 64 + lane] = acc;
}

// ---------------------------------------------------------------------------
// Global mean pool: batch is sorted, so run-length accumulate per chunk,
// flush one atomic per (chunk, graph) boundary. Thread c==0 also counts.
// ---------------------------------------------------------------------------
__global__ __launch_bounds__(128) void pool_kernel(const float* __restrict__ h,
                                                   const int* __restrict__ batch,
                                                   float* __restrict__ pool,
                                                   float* __restrict__ gcnt) {
    int c = threadIdx.x;                 // 0..127
    int n0 = blockIdx.x * 256;
    int n1 = n0 + 256;
    if (n1 > N_NODES) n1 = N_NODES;
    if (n0 >= N_NODES) return;
    float run = 0.f, cnt = 0.f;
    int g = batch[n0];
    for (int n = n0; n < n1; n++) {
        int gn = batch[n];
        if (gn != g) {
            atomicAdd(&pool[g * OUT_CH + c], run);
            if (c == 0) atomicAdd(&gcnt[g], cnt);
            run = 0.f; cnt = 0.f; g = gn;
        }
        run += h[(size_t)n * OUT_CH + c];
        if (c == 0) cnt += 1.f;
    }
    atomicAdd(&pool[g * OUT_CH + c], run);
    if (c == 0) atomicAdd(&gcnt[g], cnt);
}

__global__ __launch_bounds__(256) void final_kernel(const float* __restrict__ pool,
                                                    const float* __restrict__ gcnt,
                                                    float* __restrict__ out) {
    int i = blockIdx.x * 256 + threadIdx.x;
    if (i < N_GRAPHS * OUT_CH)
        out[i] = pool[i] / fmaxf(gcnt[i >> 7], 1.0f);
}

// ---------------------------------------------------------------------------
extern "C" void kernel_launch(void* const* d_in, const int* in_sizes, int n_in,
                              void* d_out, int out_size, void* d_ws, size_t ws_size,
                              hipStream_t stream) {
    const float* x  = (const float*)d_in[0];
    const float* W1 = (const float*)d_in[1];
    const float* b1 = (const float*)d_in[2];
    const float* W2 = (const float*)d_in[3];
    const float* b2 = (const float*)d_in[4];
    const int*   ei = (const int*)d_in[5];     // [2, E]: row0=src, row1=dst
    const int*   batch = (const int*)d_in[6];
    float* out = (float*)d_out;

    // workspace layout (all 16B-aligned by construction)
    float* h1     = (float*)d_ws;                       // 50000*256
    float* hB     = h1 + (size_t)N_NODES * HID;         // 50000*256
    float* dinv   = hB + (size_t)N_NODES * HID;         // 50000
    float* invdeg = dinv + N_NODES;                     // 50000
    int*   rowptr = (int*)(invdeg + N_NODES);           // 50001 (pad to 50016)
    int*   col    = rowptr + 50016;                     // 800000
    float* wv     = (float*)(col + N_EDGES);            // 800000
    int*   cnt    = (int*)(wv + N_EDGES);               // 50000  } zeroed
    int*   fillp  = cnt + N_NODES;                      // 50000  } zeroed
    float* gcnt   = (float*)(fillp + N_NODES);          // 64     } zeroed
    float* pool   = gcnt + N_GRAPHS;                    // 8192   } zeroed

    size_t zbytes = ((size_t)N_NODES * 2 + N_GRAPHS + (size_t)N_GRAPHS * OUT_CH) * 4;
    hipMemsetAsync(cnt, 0, zbytes, stream);

    // CSR build
    count_kernel<<<(N_EDGES + 255) / 256, 256, 0, stream>>>(ei, cnt);
    scan_kernel<<<1, 1024, 0, stream>>>(cnt, rowptr, dinv, invdeg);
    fill_kernel<<<(N_EDGES + 255) / 256, 256, 0, stream>>>(ei, rowptr, fillp, col, wv, dinv);

    // conv1
    dim3 g1((N_NODES + BM - 1) / BM, HID / BN);
    gemm_kernel<<<g1, 256, 0, stream>>>(x, W1, h1, N_NODES, HID, IN_CH);
    agg1_kernel<<<(N_NODES + 3) / 4, 256, 0, stream>>>(h1, b1, rowptr, col, wv, invdeg, hB);

    // conv2 (reuse h1 region for h2)
    dim3 g2((N_NODES + BM - 1) / BM, OUT_CH / BN);
    gemm_kernel<<<g2, 256, 0, stream>>>(hB, W2, h1, N_NODES, OUT_CH, HID);
    agg2_kernel<<<(N_NODES + 3) / 4, 256, 0, stream>>>(h1, b2, rowptr, col, wv, invdeg, hB);

    // mean pool
    pool_kernel<<<(N_NODES + 255) / 256, 128, 0, stream>>>(hB, batch, pool, gcnt);
    final_kernel<<<(N_GRAPHS * OUT_CH + 255) / 256, 256, 0, stream>>>(pool, gcnt, out);
}

// Round 2
// 639.141 us; speedup vs baseline: 1.0947x; 1.0947x over previous
//
#include <hip/hip_runtime.h>
#include <hip/hip_bf16.h>

#define N_NODES 50000
#define N_EDGES 800000
#define IN_CH 256
#define HID 256
#define OUT_CH 128
#define N_GRAPHS 64

// bf16 <-> f32 helpers (RNE on pack)
__device__ __forceinline__ float bf2f(unsigned short u) {
    union { unsigned int i; float f; } x; x.i = ((unsigned int)u) << 16; return x.f;
}
__device__ __forceinline__ unsigned short f2bf(float f) {
    union { float f; unsigned int i; } x; x.f = f;
    unsigned int r = x.i + 0x7FFFu + ((x.i >> 16) & 1u);
    return (unsigned short)(r >> 16);
}

// ---------------------------------------------------------------------------
// CSR build: histogram of dst, block scan, slot fill.
// ---------------------------------------------------------------------------
__global__ __launch_bounds__(256) void count_kernel(const int* __restrict__ ei,
                                                    int* __restrict__ cnt) {
    int e = blockIdx.x * 256 + threadIdx.x;
    if (e < N_EDGES) atomicAdd(&cnt[ei[N_EDGES + e]], 1);
}

// single block, 1024 threads, each owns 49 contiguous elements: one 10-step
// block scan (20 barriers total) instead of 49 chunked scans (~1500 barriers).
__global__ __launch_bounds__(1024) void scan_kernel(const int* __restrict__ cnt,
                                                    int* __restrict__ rowptr,
                                                    float* __restrict__ dinv,
                                                    float* __restrict__ invdeg) {
    const int PER = 49;                    // 1024*49 = 50176 >= N_NODES
    __shared__ int tmp[1024];
    int t = threadIdx.x;
    int lo = t * PER;
    int hi = lo + PER; if (hi > N_NODES) hi = N_NODES;
    int sum = 0;
    for (int i = lo; i < hi; i++) sum += cnt[i];
    tmp[t] = sum;
    __syncthreads();
    int x = sum;
    for (int off = 1; off < 1024; off <<= 1) {
        int y = (t >= off) ? tmp[t - off] : 0;
        __syncthreads();
        x += y;
        tmp[t] = x;
        __syncthreads();
    }
    int pre = x - sum;                     // exclusive prefix of this thread's span
    for (int i = lo; i < hi; i++) {
        int v = cnt[i];
        rowptr[i] = pre;
        pre += v;
        float d = (float)v + 1.0f;         // +1 self loop
        dinv[i] = rsqrtf(d);
        invdeg[i] = 1.0f / d;
    }
    if (t == 1023) rowptr[N_NODES] = pre;  // pre == total (tail thread span empty-ish)
}

__global__ __launch_bounds__(256) void fill_kernel(const int* __restrict__ ei,
                                                   const int* __restrict__ rowptr,
                                                   int* __restrict__ fillp,
                                                   int* __restrict__ col,
                                                   float* __restrict__ wv,
                                                   const float* __restrict__ dinv) {
    int e = blockIdx.x * 256 + threadIdx.x;
    if (e >= N_EDGES) return;
    int s = ei[e];
    int d = ei[N_EDGES + e];
    int p = rowptr[d] + atomicAdd(&fillp[d], 1);
    col[p] = s;
    wv[p] = dinv[s] * dinv[d];
}

// ---------------------------------------------------------------------------
// f32 tiled GEMM, bf16 output: C[M,N] = bf16(A[M,K] @ B[K,N]).
// BM=BN=64, BK=16, 256 threads, 4x4 microtile.
// ---------------------------------------------------------------------------
#define BM 64
#define BN 64
#define BK 16
__global__ __launch_bounds__(256) void gemm_kernel(const float* __restrict__ A,
                                                   const float* __restrict__ B,
                                                   unsigned short* __restrict__ C,
                                                   int M, int N, int K) {
    __shared__ float As[BK][BM];   // transposed: As[k][m]
    __shared__ float Bs[BK][BN];
    int tid = threadIdx.x;
    int bm = blockIdx.x * BM;
    int bn = blockIdx.y * BN;
    int tr = (tid >> 4) << 2;
    int tc = (tid & 15) << 2;
    int la_r = tid >> 2;
    int la_k = (tid & 3) << 2;
    int lb_k = tid >> 4;
    int lb_n = (tid & 15) << 2;
    const bool a_in = (bm + la_r) < M;
    float acc[4][4] = {};
    for (int k0 = 0; k0 < K; k0 += BK) {
        float4 av = a_in ? *(const float4*)(A + (size_t)(bm + la_r) * K + k0 + la_k)
                         : make_float4(0.f, 0.f, 0.f, 0.f);
        float4 bv = *(const float4*)(B + (size_t)(k0 + lb_k) * N + bn + lb_n);
        __syncthreads();
        As[la_k + 0][la_r] = av.x;
        As[la_k + 1][la_r] = av.y;
        As[la_k + 2][la_r] = av.z;
        As[la_k + 3][la_r] = av.w;
        *(float4*)&Bs[lb_k][lb_n] = bv;
        __syncthreads();
#pragma unroll
        for (int k = 0; k < BK; k++) {
            float4 ar = *(const float4*)&As[k][tr];
            float4 br = *(const float4*)&Bs[k][tc];
            acc[0][0] += ar.x * br.x; acc[0][1] += ar.x * br.y;
            acc[0][2] += ar.x * br.z; acc[0][3] += ar.x * br.w;
            acc[1][0] += ar.y * br.x; acc[1][1] += ar.y * br.y;
            acc[1][2] += ar.y * br.z; acc[1][3] += ar.y * br.w;
            acc[2][0] += ar.z * br.x; acc[2][1] += ar.z * br.y;
            acc[2][2] += ar.z * br.z; acc[2][3] += ar.z * br.w;
            acc[3][0] += ar.w * br.x; acc[3][1] += ar.w * br.y;
            acc[3][2] += ar.w * br.z; acc[3][3] += ar.w * br.w;
        }
    }
#pragma unroll
    for (int i = 0; i < 4; i++) {
        int r = bm + tr + i;
        if (r < M) {
            ushort4 o;
            o.x = f2bf(acc[i][0]); o.y = f2bf(acc[i][1]);
            o.z = f2bf(acc[i][2]); o.w = f2bf(acc[i][3]);
            *(ushort4*)(C + (size_t)r * N + bn + tc) = o;
        }
    }
}

// ---------------------------------------------------------------------------
// GCN aggregation, 256ch (conv1): wave/node, lane = 4 ch, bf16 gathers,
// f32 accumulate, 2-edge unroll for MLP. ELU epilogue, f32 output.
// ---------------------------------------------------------------------------
__global__ __launch_bounds__(256) void agg1_kernel(const unsigned short* __restrict__ h,
                                                   const float* __restrict__ bias,
                                                   const int* __restrict__ rowptr,
                                                   const int* __restrict__ col,
                                                   const float* __restrict__ wv,
                                                   const float* __restrict__ invdeg,
                                                   float* __restrict__ out) {
    int node = blockIdx.x * 4 + (threadIdx.x >> 6);
    if (node >= N_NODES) return;
    int lane = threadIdx.x & 63;
    const ushort4* h4 = (const ushort4*)h;
    float id = invdeg[node];
    ushort4 sv = h4[(size_t)node * 64 + lane];
    float4 acc = make_float4(bf2f(sv.x) * id, bf2f(sv.y) * id,
                             bf2f(sv.z) * id, bf2f(sv.w) * id);
    int e0 = rowptr[node], e1 = rowptr[node + 1];
    int e = e0;
    for (; e + 1 < e1; e += 2) {
        int s0 = col[e], s1 = col[e + 1];
        float w0 = wv[e], w1 = wv[e + 1];
        ushort4 v0 = h4[(size_t)s0 * 64 + lane];
        ushort4 v1 = h4[(size_t)s1 * 64 + lane];
        acc.x += bf2f(v0.x) * w0; acc.y += bf2f(v0.y) * w0;
        acc.z += bf2f(v0.z) * w0; acc.w += bf2f(v0.w) * w0;
        acc.x += bf2f(v1.x) * w1; acc.y += bf2f(v1.y) * w1;
        acc.z += bf2f(v1.z) * w1; acc.w += bf2f(v1.w) * w1;
    }
    if (e < e1) {
        int s0 = col[e];
        float w0 = wv[e];
        ushort4 v0 = h4[(size_t)s0 * 64 + lane];
        acc.x += bf2f(v0.x) * w0; acc.y += bf2f(v0.y) * w0;
        acc.z += bf2f(v0.z) * w0; acc.w += bf2f(v0.w) * w0;
    }
    float4 bb = ((const float4*)bias)[lane];
    acc.x += bb.x; acc.y += bb.y; acc.z += bb.z; acc.w += bb.w;
    acc.x = acc.x > 0.f ? acc.x : expm1f(acc.x);
    acc.y = acc.y > 0.f ? acc.y : expm1f(acc.y);
    acc.z = acc.z > 0.f ? acc.z : expm1f(acc.z);
    acc.w = acc.w > 0.f ? acc.w : expm1f(acc.w);
    ((float4*)out)[(size_t)node * 64 + lane] = acc;
}

// 128ch (conv2): wave/node, lane = 2 ch, bf16 gathers, no activation.
__global__ __launch_bounds__(256) void agg2_kernel(const unsigned short* __restrict__ h,
                                                   const float* __restrict__ bias,
                                                   const int* __restrict__ rowptr,
                                                   const int* __restrict__ col,
                                                   const float* __restrict__ wv,
                                                   const float* __restrict__ invdeg,
                                                   float* __restrict__ out) {
    int node = blockIdx.x * 4 + (threadIdx.x >> 6);
    if (node >= N_NODES) return;
    int lane = threadIdx.x & 63;
    const ushort2* h2 = (const ushort2*)h;
    float id = invdeg[node];
    ushort2 sv = h2[(size_t)node * 64 + lane];
    float2 acc = make_float2(bf2f(sv.x) * id, bf2f(sv.y) * id);
    int e0 = rowptr[node], e1 = rowptr[node + 1];
    int e = e0;
    for (; e + 1 < e1; e += 2) {
        int s0 = col[e], s1 = col[e + 1];
        float w0 = wv[e], w1 = wv[e + 1];
        ushort2 v0 = h2[(size_t)s0 * 64 + lane];
        ushort2 v1 = h2[(size_t)s1 * 64 + lane];
        acc.x += bf2f(v0.x) * w0; acc.y += bf2f(v0.y) * w0;
        acc.x += bf2f(v1.x) * w1; acc.y += bf2f(v1.y) * w1;
    }
    if (e < e1) {
        int s0 = col[e];
        float w0 = wv[e];
        ushort2 v0 = h2[(size_t)s0 * 64 + lane];
        acc.x += bf2f(v0.x) * w0; acc.y += bf2f(v0.y) * w0;
    }
    float2 bb = ((const float2*)bias)[lane];
    acc.x += bb.x; acc.y += bb.y;
    ((float2*)out)[(size_t)node * 64 + lane] = acc;
}

// ---------------------------------------------------------------------------
// Global mean pool over sorted batch: run-length accumulate per 256-node
// chunk, flush one atomic per (chunk, graph) boundary.
// ---------------------------------------------------------------------------
__global__ __launch_bounds__(128) void pool_kernel(const float* __restrict__ h,
                                                   const int* __restrict__ batch,
                                                   float* __restrict__ pool,
                                                   float* __restrict__ gcnt) {
    int c = threadIdx.x;
    int n0 = blockIdx.x * 256;
    int n1 = n0 + 256;
    if (n1 > N_NODES) n1 = N_NODES;
    if (n0 >= N_NODES) return;
    float run = 0.f, cnt = 0.f;
    int g = batch[n0];
    for (int n = n0; n < n1; n++) {
        int gn = batch[n];
        if (gn != g) {
            atomicAdd(&pool[g * OUT_CH + c], run);
            if (c == 0) atomicAdd(&gcnt[g], cnt);
            run = 0.f; cnt = 0.f; g = gn;
        }
        run += h[(size_t)n * OUT_CH + c];
        if (c == 0) cnt += 1.f;
    }
    atomicAdd(&pool[g * OUT_CH + c], run);
    if (c == 0) atomicAdd(&gcnt[g], cnt);
}

__global__ __launch_bounds__(256) void final_kernel(const float* __restrict__ pool,
                                                    const float* __restrict__ gcnt,
                                                    float* __restrict__ out) {
    int i = blockIdx.x * 256 + threadIdx.x;
    if (i < N_GRAPHS * OUT_CH)
        out[i] = pool[i] / fmaxf(gcnt[i >> 7], 1.0f);
}

// ---------------------------------------------------------------------------
extern "C" void kernel_launch(void* const* d_in, const int* in_sizes, int n_in,
                              void* d_out, int out_size, void* d_ws, size_t ws_size,
                              hipStream_t stream) {
    const float* x  = (const float*)d_in[0];
    const float* W1 = (const float*)d_in[1];
    const float* b1 = (const float*)d_in[2];
    const float* W2 = (const float*)d_in[3];
    const float* b2 = (const float*)d_in[4];
    const int*   ei = (const int*)d_in[5];
    const int*   batch = (const int*)d_in[6];
    float* out = (float*)d_out;

    // workspace layout
    unsigned short* h1b = (unsigned short*)d_ws;               // N*256 bf16 (25.6 MB)
    float* hB  = (float*)(h1b + (size_t)N_NODES * HID);        // N*256 f32  (51.2 MB)
    unsigned short* h2b = (unsigned short*)(hB + (size_t)N_NODES * HID); // N*128 bf16
    float* hC  = (float*)h1b;  // agg2 f32 output aliases h1b (dead after gemm2)
    float* dinv   = (float*)(h2b + (size_t)N_NODES * OUT_CH);
    float* invdeg = dinv + N_NODES;
    int*   rowptr = (int*)(invdeg + N_NODES);                  // 50001 (pad 50016)
    int*   col    = rowptr + 50016;
    float* wv     = (float*)(col + N_EDGES);
    int*   cnt    = (int*)(wv + N_EDGES);                      // zeroed
    int*   fillp  = cnt + N_NODES;                             // zeroed
    float* gcnt   = (float*)(fillp + N_NODES);                 // zeroed
    float* pool   = gcnt + N_GRAPHS;                           // zeroed

    size_t zbytes = ((size_t)N_NODES * 2 + N_GRAPHS + (size_t)N_GRAPHS * OUT_CH) * 4;
    hipMemsetAsync(cnt, 0, zbytes, stream);

    // CSR build
    count_kernel<<<(N_EDGES + 255) / 256, 256, 0, stream>>>(ei, cnt);
    scan_kernel<<<1, 1024, 0, stream>>>(cnt, rowptr, dinv, invdeg);
    fill_kernel<<<(N_EDGES + 255) / 256, 256, 0, stream>>>(ei, rowptr, fillp, col, wv, dinv);

    // conv1: gemm -> bf16 h1, aggregate -> f32 hB (with ELU)
    dim3 g1((N_NODES + BM - 1) / BM, HID / BN);
    gemm_kernel<<<g1, 256, 0, stream>>>(x, W1, h1b, N_NODES, HID, IN_CH);
    agg1_kernel<<<(N_NODES + 3) / 4, 256, 0, stream>>>(h1b, b1, rowptr, col, wv, invdeg, hB);

    // conv2: gemm -> bf16 h2, aggregate -> f32 hC
    dim3 g2((N_NODES + BM - 1) / BM, OUT_CH / BN);
    gemm_kernel<<<g2, 256, 0, stream>>>(hB, W2, h2b, N_NODES, OUT_CH, HID);
    agg2_kernel<<<(N_NODES + 3) / 4, 256, 0, stream>>>(h2b, b2, rowptr, col, wv, invdeg, hC);

    // mean pool
    pool_kernel<<<(N_NODES + 255) / 256, 128, 0, stream>>>(hC, batch, pool, gcnt);
    final_kernel<<<(N_GRAPHS * OUT_CH + 255) / 256, 256, 0, stream>>>(pool, gcnt, out);
}

// Round 3
// 514.977 us; speedup vs baseline: 1.3587x; 1.2411x over previous
//
#include <hip/hip_runtime.h>
#include <hip/hip_bf16.h>

#define N_NODES 50000
#define N_EDGES 800000
#define IN_CH 256
#define HID 256
#define OUT_CH 128
#define N_GRAPHS 64
#define SCAN_BLOCKS 196   // ceil(50000/256)

// bf16 <-> f32 helpers (RNE on pack)
__device__ __forceinline__ float bf2f(unsigned short u) {
    union { unsigned int i; float f; } x; x.i = ((unsigned int)u) << 16; return x.f;
}
__device__ __forceinline__ unsigned short f2bf(float f) {
    union { float f; unsigned int i; } x; x.f = f;
    unsigned int r = x.i + 0x7FFFu + ((x.i >> 16) & 1u);
    return (unsigned short)(r >> 16);
}

// ---------------------------------------------------------------------------
// CSR build: histogram, 3-phase parallel scan, slot fill (packed int2 edges).
// ---------------------------------------------------------------------------
__global__ __launch_bounds__(256) void count_kernel(const int* __restrict__ ei,
                                                    int* __restrict__ cnt) {
    int e = blockIdx.x * 256 + threadIdx.x;
    if (e < N_EDGES) atomicAdd(&cnt[ei[N_EDGES + e]], 1);
}

// phase A: block-local exclusive scan (coalesced), block total -> blocksum.
// Also emits dinv/invdeg (independent of prefix).
__global__ __launch_bounds__(256) void scan_a_kernel(const int* __restrict__ cnt,
                                                     int* __restrict__ rowptr,
                                                     int* __restrict__ blocksum,
                                                     float* __restrict__ dinv,
                                                     float* __restrict__ invdeg) {
    __shared__ int tmp[256];
    int t = threadIdx.x;
    int i = blockIdx.x * 256 + t;
    int v = (i < N_NODES) ? cnt[i] : 0;
    int x = v;
    tmp[t] = x;
    __syncthreads();
#pragma unroll
    for (int off = 1; off < 256; off <<= 1) {
        int y = (t >= off) ? tmp[t - off] : 0;
        __syncthreads();
        x += y;
        tmp[t] = x;
        __syncthreads();
    }
    if (i < N_NODES) {
        rowptr[i] = x - v;                 // exclusive within block
        float d = (float)v + 1.0f;         // +1 self loop
        dinv[i] = rsqrtf(d);
        invdeg[i] = 1.0f / d;
    }
    if (t == 255) blocksum[blockIdx.x] = x;
}

// phase B: single block scans the SCAN_BLOCKS block sums.
__global__ __launch_bounds__(256) void scan_b_kernel(const int* __restrict__ blocksum,
                                                     int* __restrict__ blockoff,
                                                     int* __restrict__ rowptr) {
    __shared__ int tmp[256];
    int t = threadIdx.x;
    int v = (t < SCAN_BLOCKS) ? blocksum[t] : 0;
    int x = v;
    tmp[t] = x;
    __syncthreads();
#pragma unroll
    for (int off = 1; off < 256; off <<= 1) {
        int y = (t >= off) ? tmp[t - off] : 0;
        __syncthreads();
        x += y;
        tmp[t] = x;
        __syncthreads();
    }
    if (t < SCAN_BLOCKS) blockoff[t] = x - v;
    if (t == 255) rowptr[N_NODES] = x;     // total
}

// phase C: add block offsets.
__global__ __launch_bounds__(256) void scan_c_kernel(int* __restrict__ rowptr,
                                                     const int* __restrict__ blockoff) {
    int i = blockIdx.x * 256 + threadIdx.x;
    if (i < N_NODES) rowptr[i] += blockoff[blockIdx.x];
}

// fill: one scattered 8B store per edge (packed {src, w_bits}).
__global__ __launch_bounds__(256) void fill_kernel(const int* __restrict__ ei,
                                                   const int* __restrict__ rowptr,
                                                   int* __restrict__ fillp,
                                                   int2* __restrict__ edge2,
                                                   const float* __restrict__ dinv) {
    int e = blockIdx.x * 256 + threadIdx.x;
    if (e >= N_EDGES) return;
    int s = ei[e];
    int d = ei[N_EDGES + e];
    int p = rowptr[d] + atomicAdd(&fillp[d], 1);
    float w = dinv[s] * dinv[d];
    edge2[p] = make_int2(s, __float_as_int(w));
}

// ---------------------------------------------------------------------------
// f32 tiled GEMM, bf16 output: C[M,N] = bf16(A[M,K] @ B[K,N]).
// ---------------------------------------------------------------------------
#define BM 64
#define BN 64
#define BK 16
__global__ __launch_bounds__(256) void gemm_kernel(const float* __restrict__ A,
                                                   const float* __restrict__ B,
                                                   unsigned short* __restrict__ C,
                                                   int M, int N, int K) {
    __shared__ float As[BK][BM];
    __shared__ float Bs[BK][BN];
    int tid = threadIdx.x;
    int bm = blockIdx.x * BM;
    int bn = blockIdx.y * BN;
    int tr = (tid >> 4) << 2;
    int tc = (tid & 15) << 2;
    int la_r = tid >> 2;
    int la_k = (tid & 3) << 2;
    int lb_k = tid >> 4;
    int lb_n = (tid & 15) << 2;
    const bool a_in = (bm + la_r) < M;
    float acc[4][4] = {};
    for (int k0 = 0; k0 < K; k0 += BK) {
        float4 av = a_in ? *(const float4*)(A + (size_t)(bm + la_r) * K + k0 + la_k)
                         : make_float4(0.f, 0.f, 0.f, 0.f);
        float4 bv = *(const float4*)(B + (size_t)(k0 + lb_k) * N + bn + lb_n);
        __syncthreads();
        As[la_k + 0][la_r] = av.x;
        As[la_k + 1][la_r] = av.y;
        As[la_k + 2][la_r] = av.z;
        As[la_k + 3][la_r] = av.w;
        *(float4*)&Bs[lb_k][lb_n] = bv;
        __syncthreads();
#pragma unroll
        for (int k = 0; k < BK; k++) {
            float4 ar = *(const float4*)&As[k][tr];
            float4 br = *(const float4*)&Bs[k][tc];
            acc[0][0] += ar.x * br.x; acc[0][1] += ar.x * br.y;
            acc[0][2] += ar.x * br.z; acc[0][3] += ar.x * br.w;
            acc[1][0] += ar.y * br.x; acc[1][1] += ar.y * br.y;
            acc[1][2] += ar.y * br.z; acc[1][3] += ar.y * br.w;
            acc[2][0] += ar.z * br.x; acc[2][1] += ar.z * br.y;
            acc[2][2] += ar.z * br.z; acc[2][3] += ar.z * br.w;
            acc[3][0] += ar.w * br.x; acc[3][1] += ar.w * br.y;
            acc[3][2] += ar.w * br.z; acc[3][3] += ar.w * br.w;
        }
    }
#pragma unroll
    for (int i = 0; i < 4; i++) {
        int r = bm + tr + i;
        if (r < M) {
            ushort4 o;
            o.x = f2bf(acc[i][0]); o.y = f2bf(acc[i][1]);
            o.z = f2bf(acc[i][2]); o.w = f2bf(acc[i][3]);
            *(ushort4*)(C + (size_t)r * N + bn + tc) = o;
        }
    }
}

// ---------------------------------------------------------------------------
// GCN aggregation, 256ch (conv1): wave/node, lane = 4 ch, bf16 gathers,
// packed int2 edge stream, f32 accumulate, ELU epilogue, f32 output.
// ---------------------------------------------------------------------------
__global__ __launch_bounds__(256) void agg1_kernel(const unsigned short* __restrict__ h,
                                                   const float* __restrict__ bias,
                                                   const int* __restrict__ rowptr,
                                                   const int2* __restrict__ edge2,
                                                   const float* __restrict__ invdeg,
                                                   float* __restrict__ out) {
    int node = blockIdx.x * 4 + (threadIdx.x >> 6);
    if (node >= N_NODES) return;
    int lane = threadIdx.x & 63;
    const ushort4* h4 = (const ushort4*)h;
    float id = invdeg[node];
    ushort4 sv = h4[(size_t)node * 64 + lane];
    float4 acc = make_float4(bf2f(sv.x) * id, bf2f(sv.y) * id,
                             bf2f(sv.z) * id, bf2f(sv.w) * id);
    int e0 = rowptr[node], e1 = rowptr[node + 1];
    int e = e0;
    for (; e + 1 < e1; e += 2) {
        int2 ed0 = edge2[e], ed1 = edge2[e + 1];
        float w0 = __int_as_float(ed0.y), w1 = __int_as_float(ed1.y);
        ushort4 v0 = h4[(size_t)ed0.x * 64 + lane];
        ushort4 v1 = h4[(size_t)ed1.x * 64 + lane];
        acc.x += bf2f(v0.x) * w0; acc.y += bf2f(v0.y) * w0;
        acc.z += bf2f(v0.z) * w0; acc.w += bf2f(v0.w) * w0;
        acc.x += bf2f(v1.x) * w1; acc.y += bf2f(v1.y) * w1;
        acc.z += bf2f(v1.z) * w1; acc.w += bf2f(v1.w) * w1;
    }
    if (e < e1) {
        int2 ed0 = edge2[e];
        float w0 = __int_as_float(ed0.y);
        ushort4 v0 = h4[(size_t)ed0.x * 64 + lane];
        acc.x += bf2f(v0.x) * w0; acc.y += bf2f(v0.y) * w0;
        acc.z += bf2f(v0.z) * w0; acc.w += bf2f(v0.w) * w0;
    }
    float4 bb = ((const float4*)bias)[lane];
    acc.x += bb.x; acc.y += bb.y; acc.z += bb.z; acc.w += bb.w;
    acc.x = acc.x > 0.f ? acc.x : expm1f(acc.x);
    acc.y = acc.y > 0.f ? acc.y : expm1f(acc.y);
    acc.z = acc.z > 0.f ? acc.z : expm1f(acc.z);
    acc.w = acc.w > 0.f ? acc.w : expm1f(acc.w);
    ((float4*)out)[(size_t)node * 64 + lane] = acc;
}

// 128ch (conv2): wave/node, lane = 2 ch, no activation.
__global__ __launch_bounds__(256) void agg2_kernel(const unsigned short* __restrict__ h,
                                                   const float* __restrict__ bias,
                                                   const int* __restrict__ rowptr,
                                                   const int2* __restrict__ edge2,
                                                   const float* __restrict__ invdeg,
                                                   float* __restrict__ out) {
    int node = blockIdx.x * 4 + (threadIdx.x >> 6);
    if (node >= N_NODES) return;
    int lane = threadIdx.x & 63;
    const ushort2* h2 = (const ushort2*)h;
    float id = invdeg[node];
    ushort2 sv = h2[(size_t)node * 64 + lane];
    float2 acc = make_float2(bf2f(sv.x) * id, bf2f(sv.y) * id);
    int e0 = rowptr[node], e1 = rowptr[node + 1];
    int e = e0;
    for (; e + 1 < e1; e += 2) {
        int2 ed0 = edge2[e], ed1 = edge2[e + 1];
        float w0 = __int_as_float(ed0.y), w1 = __int_as_float(ed1.y);
        ushort2 v0 = h2[(size_t)ed0.x * 64 + lane];
        ushort2 v1 = h2[(size_t)ed1.x * 64 + lane];
        acc.x += bf2f(v0.x) * w0; acc.y += bf2f(v0.y) * w0;
        acc.x += bf2f(v1.x) * w1; acc.y += bf2f(v1.y) * w1;
    }
    if (e < e1) {
        int2 ed0 = edge2[e];
        float w0 = __int_as_float(ed0.y);
        ushort2 v0 = h2[(size_t)ed0.x * 64 + lane];
        acc.x += bf2f(v0.x) * w0; acc.y += bf2f(v0.y) * w0;
    }
    float2 bb = ((const float2*)bias)[lane];
    acc.x += bb.x; acc.y += bb.y;
    ((float2*)out)[(size_t)node * 64 + lane] = acc;
}

// ---------------------------------------------------------------------------
// Global mean pool over sorted batch.
// ---------------------------------------------------------------------------
__global__ __launch_bounds__(128) void pool_kernel(const float* __restrict__ h,
                                                   const int* __restrict__ batch,
                                                   float* __restrict__ pool,
                                                   float* __restrict__ gcnt) {
    int c = threadIdx.x;
    int n0 = blockIdx.x * 256;
    int n1 = n0 + 256;
    if (n1 > N_NODES) n1 = N_NODES;
    if (n0 >= N_NODES) return;
    float run = 0.f, cnt = 0.f;
    int g = batch[n0];
    for (int n = n0; n < n1; n++) {
        int gn = batch[n];
        if (gn != g) {
            atomicAdd(&pool[g * OUT_CH + c], run);
            if (c == 0) atomicAdd(&gcnt[g], cnt);
            run = 0.f; cnt = 0.f; g = gn;
        }
        run += h[(size_t)n * OUT_CH + c];
        if (c == 0) cnt += 1.f;
    }
    atomicAdd(&pool[g * OUT_CH + c], run);
    if (c == 0) atomicAdd(&gcnt[g], cnt);
}

__global__ __launch_bounds__(256) void final_kernel(const float* __restrict__ pool,
                                                    const float* __restrict__ gcnt,
                                                    float* __restrict__ out) {
    int i = blockIdx.x * 256 + threadIdx.x;
    if (i < N_GRAPHS * OUT_CH)
        out[i] = pool[i] / fmaxf(gcnt[i >> 7], 1.0f);
}

// ---------------------------------------------------------------------------
extern "C" void kernel_launch(void* const* d_in, const int* in_sizes, int n_in,
                              void* d_out, int out_size, void* d_ws, size_t ws_size,
                              hipStream_t stream) {
    const float* x  = (const float*)d_in[0];
    const float* W1 = (const float*)d_in[1];
    const float* b1 = (const float*)d_in[2];
    const float* W2 = (const float*)d_in[3];
    const float* b2 = (const float*)d_in[4];
    const int*   ei = (const int*)d_in[5];
    const int*   batch = (const int*)d_in[6];
    float* out = (float*)d_out;

    // workspace layout (16B-aligned by construction)
    unsigned short* h1b = (unsigned short*)d_ws;                 // N*256 bf16
    float* hB  = (float*)(h1b + (size_t)N_NODES * HID);          // N*256 f32
    unsigned short* h2b = (unsigned short*)(hB + (size_t)N_NODES * HID); // N*128 bf16
    float* hC  = (float*)h1b;  // agg2 output aliases h1b (dead after gemm2)
    float* dinv   = (float*)(h2b + (size_t)N_NODES * OUT_CH);    // 50000
    float* invdeg = dinv + N_NODES;                              // 50000
    int*   rowptr = (int*)(invdeg + N_NODES);                    // 50001 (pad 50016)
    int2*  edge2  = (int2*)(rowptr + 50016);                     // 800000 int2 (8B-aligned)
    int*   cnt    = (int*)(edge2 + N_EDGES);                     // 50000 } zeroed
    int*   fillp  = cnt + N_NODES;                               // 50000 } zeroed
    float* gcnt   = (float*)(fillp + N_NODES);                   // 64    } zeroed
    float* pool   = gcnt + N_GRAPHS;                             // 8192  } zeroed
    int*   blocksum = (int*)(pool + N_GRAPHS * OUT_CH);          // 256
    int*   blockoff = blocksum + 256;                            // 256

    size_t zbytes = ((size_t)N_NODES * 2 + N_GRAPHS + (size_t)N_GRAPHS * OUT_CH) * 4;
    hipMemsetAsync(cnt, 0, zbytes, stream);

    // CSR build
    count_kernel<<<(N_EDGES + 255) / 256, 256, 0, stream>>>(ei, cnt);
    scan_a_kernel<<<SCAN_BLOCKS, 256, 0, stream>>>(cnt, rowptr, blocksum, dinv, invdeg);
    scan_b_kernel<<<1, 256, 0, stream>>>(blocksum, blockoff, rowptr);
    scan_c_kernel<<<SCAN_BLOCKS, 256, 0, stream>>>(rowptr, blockoff);
    fill_kernel<<<(N_EDGES + 255) / 256, 256, 0, stream>>>(ei, rowptr, fillp, edge2, dinv);

    // conv1
    dim3 g1((N_NODES + BM - 1) / BM, HID / BN);
    gemm_kernel<<<g1, 256, 0, stream>>>(x, W1, h1b, N_NODES, HID, IN_CH);
    agg1_kernel<<<(N_NODES + 3) / 4, 256, 0, stream>>>(h1b, b1, rowptr, edge2, invdeg, hB);

    // conv2
    dim3 g2((N_NODES + BM - 1) / BM, OUT_CH / BN);
    gemm_kernel<<<g2, 256, 0, stream>>>(hB, W2, h2b, N_NODES, OUT_CH, HID);
    agg2_kernel<<<(N_NODES + 3) / 4, 256, 0, stream>>>(h2b, b2, rowptr, edge2, invdeg, hC);

    // mean pool
    pool_kernel<<<(N_NODES + 255) / 256, 128, 0, stream>>>(hC, batch, pool, gcnt);
    final_kernel<<<(N_GRAPHS * OUT_CH + 255) / 256, 256, 0, stream>>>(pool, gcnt, out);
}

// Round 4
// 410.300 us; speedup vs baseline: 1.7053x; 1.2551x over previous
//
#include <hip/hip_runtime.h>
#include <hip/hip_bf16.h>

#define N_NODES 50000
#define N_EDGES 800000
#define IN_CH 256
#define HID 256
#define OUT_CH 128
#define N_GRAPHS 64
#define SCAN_BLOCKS 196   // ceil(50000/256)
#define M_PAD 50048       // 391 * 128

typedef __bf16 bf16x8 __attribute__((ext_vector_type(8)));
typedef float f32x4 __attribute__((ext_vector_type(4)));

// bf16 <-> f32 helpers (RNE on pack)
__device__ __forceinline__ float bf2f(unsigned short u) {
    union { unsigned int i; float f; } x; x.i = ((unsigned int)u) << 16; return x.f;
}
__device__ __forceinline__ unsigned short f2bf(float f) {
    union { float f; unsigned int i; } x; x.f = f;
    unsigned int r = x.i + 0x7FFFu + ((x.i >> 16) & 1u);
    return (unsigned short)(r >> 16);
}

__device__ __forceinline__ void load16(const void* g, void* l) {
    __builtin_amdgcn_global_load_lds(
        (const __attribute__((address_space(1))) void*)g,
        (__attribute__((address_space(3))) void*)l, 16, 0, 0);
}

// ---------------------------------------------------------------------------
// CSR build: histogram, 3-phase parallel scan, slot fill (packed int2 edges).
// ---------------------------------------------------------------------------
__global__ __launch_bounds__(256) void count_kernel(const int* __restrict__ ei,
                                                    int* __restrict__ cnt) {
    int e = blockIdx.x * 256 + threadIdx.x;
    if (e < N_EDGES) atomicAdd(&cnt[ei[N_EDGES + e]], 1);
}

__global__ __launch_bounds__(256) void scan_a_kernel(const int* __restrict__ cnt,
                                                     int* __restrict__ rowptr,
                                                     int* __restrict__ blocksum,
                                                     float* __restrict__ dinv,
                                                     float* __restrict__ invdeg) {
    __shared__ int tmp[256];
    int t = threadIdx.x;
    int i = blockIdx.x * 256 + t;
    int v = (i < N_NODES) ? cnt[i] : 0;
    int x = v;
    tmp[t] = x;
    __syncthreads();
#pragma unroll
    for (int off = 1; off < 256; off <<= 1) {
        int y = (t >= off) ? tmp[t - off] : 0;
        __syncthreads();
        x += y;
        tmp[t] = x;
        __syncthreads();
    }
    if (i < N_NODES) {
        rowptr[i] = x - v;
        float d = (float)v + 1.0f;         // +1 self loop
        dinv[i] = rsqrtf(d);
        invdeg[i] = 1.0f / d;
    }
    if (t == 255) blocksum[blockIdx.x] = x;
}

__global__ __launch_bounds__(256) void scan_b_kernel(const int* __restrict__ blocksum,
                                                     int* __restrict__ blockoff,
                                                     int* __restrict__ rowptr) {
    __shared__ int tmp[256];
    int t = threadIdx.x;
    int v = (t < SCAN_BLOCKS) ? blocksum[t] : 0;
    int x = v;
    tmp[t] = x;
    __syncthreads();
#pragma unroll
    for (int off = 1; off < 256; off <<= 1) {
        int y = (t >= off) ? tmp[t - off] : 0;
        __syncthreads();
        x += y;
        tmp[t] = x;
        __syncthreads();
    }
    if (t < SCAN_BLOCKS) blockoff[t] = x - v;
    if (t == 255) rowptr[N_NODES] = x;
}

__global__ __launch_bounds__(256) void scan_c_kernel(int* __restrict__ rowptr,
                                                     const int* __restrict__ blockoff) {
    int i = blockIdx.x * 256 + threadIdx.x;
    if (i < N_NODES) rowptr[i] += blockoff[blockIdx.x];
}

__global__ __launch_bounds__(256) void fill_kernel(const int* __restrict__ ei,
                                                   const int* __restrict__ rowptr,
                                                   int* __restrict__ fillp,
                                                   int2* __restrict__ edge2,
                                                   const float* __restrict__ dinv) {
    int e = blockIdx.x * 256 + threadIdx.x;
    if (e >= N_EDGES) return;
    int s = ei[e];
    int d = ei[N_EDGES + e];
    int p = rowptr[d] + atomicAdd(&fillp[d], 1);
    float w = dinv[s] * dinv[d];
    edge2[p] = make_int2(s, __float_as_int(w));
}

// ---------------------------------------------------------------------------
// Converts: x f32 -> bf16 padded; W1/W2 f32 -> bf16 transposed [N][K].
// ---------------------------------------------------------------------------
__global__ __launch_bounds__(256) void cvt_x_kernel(const float* __restrict__ x,
                                                    unsigned short* __restrict__ xb) {
    int i = blockIdx.x * 256 + threadIdx.x;          // float4 index
    if (i >= M_PAD * (IN_CH / 4)) return;
    ushort4 o;
    if (i < N_NODES * (IN_CH / 4)) {
        float4 v = ((const float4*)x)[i];
        o.x = f2bf(v.x); o.y = f2bf(v.y); o.z = f2bf(v.z); o.w = f2bf(v.w);
    } else {
        o = make_ushort4(0, 0, 0, 0);
    }
    ((ushort4*)xb)[i] = o;
}

__global__ __launch_bounds__(256) void cvt_w_kernel(const float* __restrict__ W1,
                                                    const float* __restrict__ W2,
                                                    unsigned short* __restrict__ w1t,
                                                    unsigned short* __restrict__ w2t) {
    int i = blockIdx.x * 256 + threadIdx.x;
    if (i < HID * IN_CH) {                            // W1t[n][k] = W1[k][n]
        int n = i >> 8, k = i & 255;
        w1t[i] = f2bf(W1[k * HID + n]);
    } else if (i < HID * IN_CH + OUT_CH * HID) {      // W2t[n][k] = W2[k][n]
        int j = i - HID * IN_CH;
        int n = j >> 8, k = j & 255;
        w2t[j] = f2bf(W2[k * OUT_CH + n]);
    }
}

// ---------------------------------------------------------------------------
// bf16 MFMA GEMM: C[M_PAD][N] = A[M_PAD][256] @ Bt[N][256]^T, all bf16.
// 128x128 tile, 4 waves 2x2, each 64x64 = 4x4 mfma_f32_16x16x32_bf16.
// global_load_lds width=16 staging; XOR chunk swizzle (2-way LDS alias only).
// ---------------------------------------------------------------------------
__global__ __launch_bounds__(256) void gemm_mfma_kernel(
        const unsigned short* __restrict__ A,
        const unsigned short* __restrict__ Bt,
        unsigned short* __restrict__ C,
        int N) {
    const int K = 256;
    __shared__ char As[8192];   // [128 rows][32 bf16], 16B chunks XOR-swizzled
    __shared__ char Bs[8192];
    int tid = threadIdx.x;
    int bm = blockIdx.x * 128;
    int bn = blockIdx.y * 128;
    int lane = tid & 63, wave = tid >> 6;
    int lane15 = lane & 15, quad = lane >> 4;
    int wm0 = (wave >> 1) << 6;
    int wn0 = (wave & 1) << 6;

    // staging: slot s holds global chunk (row=s>>2, q=(s&3)^((row>>1)&3))
    int s1 = tid, s2 = tid + 256;
    int r1 = s1 >> 2, q1 = (s1 & 3) ^ ((r1 >> 1) & 3);
    int r2 = s2 >> 2, q2 = (s2 & 3) ^ ((r2 >> 1) & 3);
    const char* gA1 = (const char*)(A + (size_t)(bm + r1) * K) + (q1 << 4);
    const char* gA2 = (const char*)(A + (size_t)(bm + r2) * K) + (q2 << 4);
    const char* gB1 = (const char*)(Bt + (size_t)(bn + r1) * K) + (q1 << 4);
    const char* gB2 = (const char*)(Bt + (size_t)(bn + r2) * K) + (q2 << 4);
    char* lA1 = As + (wave << 10);
    char* lA2 = As + 4096 + (wave << 10);
    char* lB1 = Bs + (wave << 10);
    char* lB2 = Bs + 4096 + (wave << 10);

    int swm = (lane15 >> 1) & 3;   // frag-read swizzle term
    f32x4 acc[4][4];
#pragma unroll
    for (int mt = 0; mt < 4; mt++)
#pragma unroll
        for (int nt = 0; nt < 4; nt++)
            acc[mt][nt] = (f32x4){0.f, 0.f, 0.f, 0.f};

    for (int k0 = 0; k0 < K; k0 += 32) {
        __syncthreads();
        load16(gA1 + (k0 << 1), lA1);
        load16(gA2 + (k0 << 1), lA2);
        load16(gB1 + (k0 << 1), lB1);
        load16(gB2 + (k0 << 1), lB2);
        __syncthreads();
        bf16x8 af[4], bfr[4];
#pragma unroll
        for (int t = 0; t < 4; t++) {
            int ra = wm0 + t * 16 + lane15;
            af[t] = *(const bf16x8*)(As + ra * 64 + ((quad ^ swm) << 4));
            int rb = wn0 + t * 16 + lane15;
            bfr[t] = *(const bf16x8*)(Bs + rb * 64 + ((quad ^ swm) << 4));
        }
#pragma unroll
        for (int mt = 0; mt < 4; mt++)
#pragma unroll
            for (int nt = 0; nt < 4; nt++)
                acc[mt][nt] = __builtin_amdgcn_mfma_f32_16x16x32_bf16(
                    af[mt], bfr[nt], acc[mt][nt], 0, 0, 0);
    }

#pragma unroll
    for (int mt = 0; mt < 4; mt++) {
        int rowb = bm + wm0 + mt * 16 + quad * 4;
#pragma unroll
        for (int nt = 0; nt < 4; nt++) {
            int col = bn + wn0 + nt * 16 + lane15;
            f32x4 a = acc[mt][nt];
            C[(size_t)(rowb + 0) * N + col] = f2bf(a[0]);
            C[(size_t)(rowb + 1) * N + col] = f2bf(a[1]);
            C[(size_t)(rowb + 2) * N + col] = f2bf(a[2]);
            C[(size_t)(rowb + 3) * N + col] = f2bf(a[3]);
        }
    }
}

// ---------------------------------------------------------------------------
// GCN aggregation, 256ch (conv1): wave/node, lane = 4ch, bf16 gathers,
// f32 accumulate, ELU, bf16 output (feeds gemm2 directly).
// ---------------------------------------------------------------------------
__global__ __launch_bounds__(256) void agg1_kernel(const unsigned short* __restrict__ h,
                                                   const float* __restrict__ bias,
                                                   const int* __restrict__ rowptr,
                                                   const int2* __restrict__ edge2,
                                                   const float* __restrict__ invdeg,
                                                   unsigned short* __restrict__ out) {
    int node = blockIdx.x * 4 + (threadIdx.x >> 6);
    if (node >= N_NODES) return;
    int lane = threadIdx.x & 63;
    const ushort4* h4 = (const ushort4*)h;
    float id = invdeg[node];
    ushort4 sv = h4[(size_t)node * 64 + lane];
    float4 acc = make_float4(bf2f(sv.x) * id, bf2f(sv.y) * id,
                             bf2f(sv.z) * id, bf2f(sv.w) * id);
    int e0 = rowptr[node], e1 = rowptr[node + 1];
    int e = e0;
    for (; e + 1 < e1; e += 2) {
        int2 ed0 = edge2[e], ed1 = edge2[e + 1];
        float w0 = __int_as_float(ed0.y), w1 = __int_as_float(ed1.y);
        ushort4 v0 = h4[(size_t)ed0.x * 64 + lane];
        ushort4 v1 = h4[(size_t)ed1.x * 64 + lane];
        acc.x += bf2f(v0.x) * w0; acc.y += bf2f(v0.y) * w0;
        acc.z += bf2f(v0.z) * w0; acc.w += bf2f(v0.w) * w0;
        acc.x += bf2f(v1.x) * w1; acc.y += bf2f(v1.y) * w1;
        acc.z += bf2f(v1.z) * w1; acc.w += bf2f(v1.w) * w1;
    }
    if (e < e1) {
        int2 ed0 = edge2[e];
        float w0 = __int_as_float(ed0.y);
        ushort4 v0 = h4[(size_t)ed0.x * 64 + lane];
        acc.x += bf2f(v0.x) * w0; acc.y += bf2f(v0.y) * w0;
        acc.z += bf2f(v0.z) * w0; acc.w += bf2f(v0.w) * w0;
    }
    float4 bb = ((const float4*)bias)[lane];
    acc.x += bb.x; acc.y += bb.y; acc.z += bb.z; acc.w += bb.w;
    acc.x = acc.x > 0.f ? acc.x : expm1f(acc.x);
    acc.y = acc.y > 0.f ? acc.y : expm1f(acc.y);
    acc.z = acc.z > 0.f ? acc.z : expm1f(acc.z);
    acc.w = acc.w > 0.f ? acc.w : expm1f(acc.w);
    ushort4 o;
    o.x = f2bf(acc.x); o.y = f2bf(acc.y); o.z = f2bf(acc.z); o.w = f2bf(acc.w);
    ((ushort4*)out)[(size_t)node * 64 + lane] = o;
}

// 128ch (conv2): wave/node, lane = 2ch, no activation, f32 output.
__global__ __launch_bounds__(256) void agg2_kernel(const unsigned short* __restrict__ h,
                                                   const float* __restrict__ bias,
                                                   const int* __restrict__ rowptr,
                                                   const int2* __restrict__ edge2,
                                                   const float* __restrict__ invdeg,
                                                   float* __restrict__ out) {
    int node = blockIdx.x * 4 + (threadIdx.x >> 6);
    if (node >= N_NODES) return;
    int lane = threadIdx.x & 63;
    const ushort2* h2 = (const ushort2*)h;
    float id = invdeg[node];
    ushort2 sv = h2[(size_t)node * 64 + lane];
    float2 acc = make_float2(bf2f(sv.x) * id, bf2f(sv.y) * id);
    int e0 = rowptr[node], e1 = rowptr[node + 1];
    int e = e0;
    for (; e + 1 < e1; e += 2) {
        int2 ed0 = edge2[e], ed1 = edge2[e + 1];
        float w0 = __int_as_float(ed0.y), w1 = __int_as_float(ed1.y);
        ushort2 v0 = h2[(size_t)ed0.x * 64 + lane];
        ushort2 v1 = h2[(size_t)ed1.x * 64 + lane];
        acc.x += bf2f(v0.x) * w0; acc.y += bf2f(v0.y) * w0;
        acc.x += bf2f(v1.x) * w1; acc.y += bf2f(v1.y) * w1;
    }
    if (e < e1) {
        int2 ed0 = edge2[e];
        float w0 = __int_as_float(ed0.y);
        ushort2 v0 = h2[(size_t)ed0.x * 64 + lane];
        acc.x += bf2f(v0.x) * w0; acc.y += bf2f(v0.y) * w0;
    }
    float2 bb = ((const float2*)bias)[lane];
    acc.x += bb.x; acc.y += bb.y;
    ((float2*)out)[(size_t)node * 64 + lane] = acc;
}

// ---------------------------------------------------------------------------
// Global mean pool over sorted batch.
// ---------------------------------------------------------------------------
__global__ __launch_bounds__(128) void pool_kernel(const float* __restrict__ h,
                                                   const int* __restrict__ batch,
                                                   float* __restrict__ pool,
                                                   float* __restrict__ gcnt) {
    int c = threadIdx.x;
    int n0 = blockIdx.x * 256;
    int n1 = n0 + 256;
    if (n1 > N_NODES) n1 = N_NODES;
    if (n0 >= N_NODES) return;
    float run = 0.f, cnt = 0.f;
    int g = batch[n0];
    for (int n = n0; n < n1; n++) {
        int gn = batch[n];
        if (gn != g) {
            atomicAdd(&pool[g * OUT_CH + c], run);
            if (c == 0) atomicAdd(&gcnt[g], cnt);
            run = 0.f; cnt = 0.f; g = gn;
        }
        run += h[(size_t)n * OUT_CH + c];
        if (c == 0) cnt += 1.f;
    }
    atomicAdd(&pool[g * OUT_CH + c], run);
    if (c == 0) atomicAdd(&gcnt[g], cnt);
}

__global__ __launch_bounds__(256) void final_kernel(const float* __restrict__ pool,
                                                    const float* __restrict__ gcnt,
                                                    float* __restrict__ out) {
    int i = blockIdx.x * 256 + threadIdx.x;
    if (i < N_GRAPHS * OUT_CH)
        out[i] = pool[i] / fmaxf(gcnt[i >> 7], 1.0f);
}

// ---------------------------------------------------------------------------
extern "C" void kernel_launch(void* const* d_in, const int* in_sizes, int n_in,
                              void* d_out, int out_size, void* d_ws, size_t ws_size,
                              hipStream_t stream) {
    const float* x  = (const float*)d_in[0];
    const float* W1 = (const float*)d_in[1];
    const float* b1 = (const float*)d_in[2];
    const float* W2 = (const float*)d_in[3];
    const float* b2 = (const float*)d_in[4];
    const int*   ei = (const int*)d_in[5];
    const int*   batch = (const int*)d_in[6];
    float* out = (float*)d_out;

    // workspace layout (16B-aligned by construction)
    unsigned short* xb  = (unsigned short*)d_ws;                 // M_PAD*256 bf16
    unsigned short* h1b = xb  + (size_t)M_PAD * HID;             // M_PAD*256 bf16
    unsigned short* hBb = h1b + (size_t)M_PAD * HID;             // M_PAD*256 bf16
    unsigned short* h2b = hBb + (size_t)M_PAD * HID;             // M_PAD*128 bf16
    unsigned short* w1t = h2b + (size_t)M_PAD * OUT_CH;          // 256*256
    unsigned short* w2t = w1t + HID * IN_CH;                     // 128*256
    float* hC  = (float*)xb;   // agg2 f32 out aliases xb (xb dead after gemm1)
    float* dinv   = (float*)(w2t + OUT_CH * HID);                // 50000
    float* invdeg = dinv + N_NODES;                              // 50000
    int*   rowptr = (int*)(invdeg + N_NODES);                    // 50001 (pad 50016)
    int2*  edge2  = (int2*)(rowptr + 50016);                     // 800000 int2
    int*   cnt    = (int*)(edge2 + N_EDGES);                     // 50000 } zeroed
    int*   fillp  = cnt + N_NODES;                               // 50000 } zeroed
    float* gcnt   = (float*)(fillp + N_NODES);                   // 64    } zeroed
    float* pool   = gcnt + N_GRAPHS;                             // 8192  } zeroed
    int*   blocksum = (int*)(pool + N_GRAPHS * OUT_CH);          // 256
    int*   blockoff = blocksum + 256;                            // 256

    size_t zbytes = ((size_t)N_NODES * 2 + N_GRAPHS + (size_t)N_GRAPHS * OUT_CH) * 4;
    hipMemsetAsync(cnt, 0, zbytes, stream);

    // CSR build
    count_kernel<<<(N_EDGES + 255) / 256, 256, 0, stream>>>(ei, cnt);
    scan_a_kernel<<<SCAN_BLOCKS, 256, 0, stream>>>(cnt, rowptr, blocksum, dinv, invdeg);
    scan_b_kernel<<<1, 256, 0, stream>>>(blocksum, blockoff, rowptr);
    scan_c_kernel<<<SCAN_BLOCKS, 256, 0, stream>>>(rowptr, blockoff);
    fill_kernel<<<(N_EDGES + 255) / 256, 256, 0, stream>>>(ei, rowptr, fillp, edge2, dinv);

    // converts
    cvt_x_kernel<<<(M_PAD * (IN_CH / 4) + 255) / 256, 256, 0, stream>>>(x, xb);
    cvt_w_kernel<<<(HID * IN_CH + OUT_CH * HID + 255) / 256, 256, 0, stream>>>(W1, W2, w1t, w2t);

    // conv1: MFMA gemm -> bf16 h1, aggregate(+ELU) -> bf16 hB
    dim3 g1(M_PAD / 128, HID / 128);
    gemm_mfma_kernel<<<g1, 256, 0, stream>>>(xb, w1t, h1b, HID);
    agg1_kernel<<<(N_NODES + 3) / 4, 256, 0, stream>>>(h1b, b1, rowptr, edge2, invdeg, hBb);

    // conv2: MFMA gemm -> bf16 h2, aggregate -> f32 hC
    dim3 g2(M_PAD / 128, OUT_CH / 128);
    gemm_mfma_kernel<<<g2, 256, 0, stream>>>(hBb, w2t, h2b, OUT_CH);
    agg2_kernel<<<(N_NODES + 3) / 4, 256, 0, stream>>>(h2b, b2, rowptr, edge2, invdeg, hC);

    // mean pool
    pool_kernel<<<(N_NODES + 255) / 256, 128, 0, stream>>>(hC, batch, pool, gcnt);
    final_kernel<<<(N_GRAPHS * OUT_CH + 255) / 256, 256, 0, stream>>>(pool, gcnt, out);
}

// Round 5
// 356.801 us; speedup vs baseline: 1.9610x; 1.1499x over previous
//
#include <hip/hip_runtime.h>
#include <hip/hip_bf16.h>

#define N_NODES 50000
#define N_EDGES 800000
#define IN_CH 256
#define HID 256
#define OUT_CH 128
#define N_GRAPHS 64
#define SCAN_BLOCKS 196   // ceil(50000/256)
#define M_PAD 50048       // 391 * 128
#define POOL_CHUNK 32
#define POOL_BLOCKS ((N_NODES + POOL_CHUNK - 1) / POOL_CHUNK)

typedef __bf16 bf16x8 __attribute__((ext_vector_type(8)));
typedef float f32x4 __attribute__((ext_vector_type(4)));

// bf16 <-> f32 helpers (RNE on pack)
__device__ __forceinline__ float bf2f(unsigned short u) {
    union { unsigned int i; float f; } x; x.i = ((unsigned int)u) << 16; return x.f;
}
__device__ __forceinline__ unsigned short f2bf(float f) {
    union { float f; unsigned int i; } x; x.f = f;
    unsigned int r = x.i + 0x7FFFu + ((x.i >> 16) & 1u);
    return (unsigned short)(r >> 16);
}

__device__ __forceinline__ void load16(const void* g, void* l) {
    __builtin_amdgcn_global_load_lds(
        (const __attribute__((address_space(1))) void*)g,
        (__attribute__((address_space(3))) void*)l, 16, 0, 0);
}

// ---------------------------------------------------------------------------
// CSR build: histogram, 3-phase parallel scan, slot fill (packed int2 edges).
// ---------------------------------------------------------------------------
__global__ __launch_bounds__(256) void count_kernel(const int* __restrict__ ei,
                                                    int* __restrict__ cnt) {
    int e = blockIdx.x * 256 + threadIdx.x;
    if (e < N_EDGES) atomicAdd(&cnt[ei[N_EDGES + e]], 1);
}

__global__ __launch_bounds__(256) void scan_a_kernel(const int* __restrict__ cnt,
                                                     int* __restrict__ rowptr,
                                                     int* __restrict__ blocksum,
                                                     float* __restrict__ dinv,
                                                     float* __restrict__ invdeg) {
    __shared__ int tmp[256];
    int t = threadIdx.x;
    int i = blockIdx.x * 256 + t;
    int v = (i < N_NODES) ? cnt[i] : 0;
    int x = v;
    tmp[t] = x;
    __syncthreads();
#pragma unroll
    for (int off = 1; off < 256; off <<= 1) {
        int y = (t >= off) ? tmp[t - off] : 0;
        __syncthreads();
        x += y;
        tmp[t] = x;
        __syncthreads();
    }
    if (i < N_NODES) {
        rowptr[i] = x - v;
        float d = (float)v + 1.0f;         // +1 self loop
        dinv[i] = rsqrtf(d);
        invdeg[i] = 1.0f / d;
    }
    if (t == 255) blocksum[blockIdx.x] = x;
}

__global__ __launch_bounds__(256) void scan_b_kernel(const int* __restrict__ blocksum,
                                                     int* __restrict__ blockoff,
                                                     int* __restrict__ rowptr) {
    __shared__ int tmp[256];
    int t = threadIdx.x;
    int v = (t < SCAN_BLOCKS) ? blocksum[t] : 0;
    int x = v;
    tmp[t] = x;
    __syncthreads();
#pragma unroll
    for (int off = 1; off < 256; off <<= 1) {
        int y = (t >= off) ? tmp[t - off] : 0;
        __syncthreads();
        x += y;
        tmp[t] = x;
        __syncthreads();
    }
    if (t < SCAN_BLOCKS) blockoff[t] = x - v;
    if (t == 255) rowptr[N_NODES] = x;
}

__global__ __launch_bounds__(256) void scan_c_kernel(int* __restrict__ rowptr,
                                                     const int* __restrict__ blockoff) {
    int i = blockIdx.x * 256 + threadIdx.x;
    if (i < N_NODES) rowptr[i] += blockoff[blockIdx.x];
}

__global__ __launch_bounds__(256) void fill_kernel(const int* __restrict__ ei,
                                                   const int* __restrict__ rowptr,
                                                   int* __restrict__ fillp,
                                                   int2* __restrict__ edge2,
                                                   const float* __restrict__ dinv) {
    int e = blockIdx.x * 256 + threadIdx.x;
    if (e >= N_EDGES) return;
    int s = ei[e];
    int d = ei[N_EDGES + e];
    int p = rowptr[d] + atomicAdd(&fillp[d], 1);
    float w = dinv[s] * dinv[d];
    edge2[p] = make_int2(s, __float_as_int(w));
}

// ---------------------------------------------------------------------------
// Converts: x f32 -> bf16 padded; W1/W2 f32 -> bf16 transposed [N][K].
// ---------------------------------------------------------------------------
__global__ __launch_bounds__(256) void cvt_x_kernel(const float* __restrict__ x,
                                                    unsigned short* __restrict__ xb) {
    int i = blockIdx.x * 256 + threadIdx.x;          // float4 index
    if (i >= M_PAD * (IN_CH / 4)) return;
    ushort4 o;
    if (i < N_NODES * (IN_CH / 4)) {
        float4 v = ((const float4*)x)[i];
        o.x = f2bf(v.x); o.y = f2bf(v.y); o.z = f2bf(v.z); o.w = f2bf(v.w);
    } else {
        o = make_ushort4(0, 0, 0, 0);
    }
    ((ushort4*)xb)[i] = o;
}

__global__ __launch_bounds__(256) void cvt_w_kernel(const float* __restrict__ W1,
                                                    const float* __restrict__ W2,
                                                    unsigned short* __restrict__ w1t,
                                                    unsigned short* __restrict__ w2t) {
    int i = blockIdx.x * 256 + threadIdx.x;
    if (i < HID * IN_CH) {                            // W1t[n][k] = W1[k][n]
        int n = i >> 8, k = i & 255;
        w1t[i] = f2bf(W1[k * HID + n]);
    } else if (i < HID * IN_CH + OUT_CH * HID) {      // W2t[n][k] = W2[k][n]
        int j = i - HID * IN_CH;
        int n = j >> 8, k = j & 255;
        w2t[j] = f2bf(W2[k * OUT_CH + n]);
    }
}

// ---------------------------------------------------------------------------
// bf16 MFMA GEMM: C[M_PAD][N] = A[M_PAD][256] @ Bt[N][256]^T, all bf16.
// 128x128 tile, 4 waves 2x2, each 64x64 = 4x4 mfma_f32_16x16x32_bf16.
// ---------------------------------------------------------------------------
__global__ __launch_bounds__(256) void gemm_mfma_kernel(
        const unsigned short* __restrict__ A,
        const unsigned short* __restrict__ Bt,
        unsigned short* __restrict__ C,
        int N) {
    const int K = 256;
    __shared__ char As[8192];   // [128 rows][32 bf16], 16B chunks XOR-swizzled
    __shared__ char Bs[8192];
    int tid = threadIdx.x;
    int bm = blockIdx.x * 128;
    int bn = blockIdx.y * 128;
    int lane = tid & 63, wave = tid >> 6;
    int lane15 = lane & 15, quad = lane >> 4;
    int wm0 = (wave >> 1) << 6;
    int wn0 = (wave & 1) << 6;

    int s1 = tid, s2 = tid + 256;
    int r1 = s1 >> 2, q1 = (s1 & 3) ^ ((r1 >> 1) & 3);
    int r2 = s2 >> 2, q2 = (s2 & 3) ^ ((r2 >> 1) & 3);
    const char* gA1 = (const char*)(A + (size_t)(bm + r1) * K) + (q1 << 4);
    const char* gA2 = (const char*)(A + (size_t)(bm + r2) * K) + (q2 << 4);
    const char* gB1 = (const char*)(Bt + (size_t)(bn + r1) * K) + (q1 << 4);
    const char* gB2 = (const char*)(Bt + (size_t)(bn + r2) * K) + (q2 << 4);
    char* lA1 = As + (wave << 10);
    char* lA2 = As + 4096 + (wave << 10);
    char* lB1 = Bs + (wave << 10);
    char* lB2 = Bs + 4096 + (wave << 10);

    int swm = (lane15 >> 1) & 3;
    f32x4 acc[4][4];
#pragma unroll
    for (int mt = 0; mt < 4; mt++)
#pragma unroll
        for (int nt = 0; nt < 4; nt++)
            acc[mt][nt] = (f32x4){0.f, 0.f, 0.f, 0.f};

    for (int k0 = 0; k0 < K; k0 += 32) {
        __syncthreads();
        load16(gA1 + (k0 << 1), lA1);
        load16(gA2 + (k0 << 1), lA2);
        load16(gB1 + (k0 << 1), lB1);
        load16(gB2 + (k0 << 1), lB2);
        __syncthreads();
        bf16x8 af[4], bfr[4];
#pragma unroll
        for (int t = 0; t < 4; t++) {
            int ra = wm0 + t * 16 + lane15;
            af[t] = *(const bf16x8*)(As + ra * 64 + ((quad ^ swm) << 4));
            int rb = wn0 + t * 16 + lane15;
            bfr[t] = *(const bf16x8*)(Bs + rb * 64 + ((quad ^ swm) << 4));
        }
#pragma unroll
        for (int mt = 0; mt < 4; mt++)
#pragma unroll
            for (int nt = 0; nt < 4; nt++)
                acc[mt][nt] = __builtin_amdgcn_mfma_f32_16x16x32_bf16(
                    af[mt], bfr[nt], acc[mt][nt], 0, 0, 0);
    }

#pragma unroll
    for (int mt = 0; mt < 4; mt++) {
        int rowb = bm + wm0 + mt * 16 + quad * 4;
#pragma unroll
        for (int nt = 0; nt < 4; nt++) {
            int col = bn + wn0 + nt * 16 + lane15;
            f32x4 a = acc[mt][nt];
            C[(size_t)(rowb + 0) * N + col] = f2bf(a[0]);
            C[(size_t)(rowb + 1) * N + col] = f2bf(a[1]);
            C[(size_t)(rowb + 2) * N + col] = f2bf(a[2]);
            C[(size_t)(rowb + 3) * N + col] = f2bf(a[3]);
        }
    }
}

// ---------------------------------------------------------------------------
// GCN aggregation, 256ch (conv1): wave/node, lane = 4ch, bf16 gathers,
// f32 accumulate, ELU, bf16 output (feeds gemm2 directly).
// ---------------------------------------------------------------------------
__global__ __launch_bounds__(256) void agg1_kernel(const unsigned short* __restrict__ h,
                                                   const float* __restrict__ bias,
                                                   const int* __restrict__ rowptr,
                                                   const int2* __restrict__ edge2,
                                                   const float* __restrict__ invdeg,
                                                   unsigned short* __restrict__ out) {
    int node = blockIdx.x * 4 + (threadIdx.x >> 6);
    if (node >= N_NODES) return;
    int lane = threadIdx.x & 63;
    const ushort4* h4 = (const ushort4*)h;
    float id = invdeg[node];
    ushort4 sv = h4[(size_t)node * 64 + lane];
    float4 acc = make_float4(bf2f(sv.x) * id, bf2f(sv.y) * id,
                             bf2f(sv.z) * id, bf2f(sv.w) * id);
    int e0 = rowptr[node], e1 = rowptr[node + 1];
    int e = e0;
    for (; e + 1 < e1; e += 2) {
        int2 ed0 = edge2[e], ed1 = edge2[e + 1];
        float w0 = __int_as_float(ed0.y), w1 = __int_as_float(ed1.y);
        ushort4 v0 = h4[(size_t)ed0.x * 64 + lane];
        ushort4 v1 = h4[(size_t)ed1.x * 64 + lane];
        acc.x += bf2f(v0.x) * w0; acc.y += bf2f(v0.y) * w0;
        acc.z += bf2f(v0.z) * w0; acc.w += bf2f(v0.w) * w0;
        acc.x += bf2f(v1.x) * w1; acc.y += bf2f(v1.y) * w1;
        acc.z += bf2f(v1.z) * w1; acc.w += bf2f(v1.w) * w1;
    }
    if (e < e1) {
        int2 ed0 = edge2[e];
        float w0 = __int_as_float(ed0.y);
        ushort4 v0 = h4[(size_t)ed0.x * 64 + lane];
        acc.x += bf2f(v0.x) * w0; acc.y += bf2f(v0.y) * w0;
        acc.z += bf2f(v0.z) * w0; acc.w += bf2f(v0.w) * w0;
    }
    float4 bb = ((const float4*)bias)[lane];
    acc.x += bb.x; acc.y += bb.y; acc.z += bb.z; acc.w += bb.w;
    acc.x = acc.x > 0.f ? acc.x : expm1f(acc.x);
    acc.y = acc.y > 0.f ? acc.y : expm1f(acc.y);
    acc.z = acc.z > 0.f ? acc.z : expm1f(acc.z);
    acc.w = acc.w > 0.f ? acc.w : expm1f(acc.w);
    ushort4 o;
    o.x = f2bf(acc.x); o.y = f2bf(acc.y); o.z = f2bf(acc.z); o.w = f2bf(acc.w);
    ((ushort4*)out)[(size_t)node * 64 + lane] = o;
}

// 128ch (conv2): wave/node, lane = 2ch, no activation, f32 output.
__global__ __launch_bounds__(256) void agg2_kernel(const unsigned short* __restrict__ h,
                                                   const float* __restrict__ bias,
                                                   const int* __restrict__ rowptr,
                                                   const int2* __restrict__ edge2,
                                                   const float* __restrict__ invdeg,
                                                   float* __restrict__ out) {
    int node = blockIdx.x * 4 + (threadIdx.x >> 6);
    if (node >= N_NODES) return;
    int lane = threadIdx.x & 63;
    const ushort2* h2 = (const ushort2*)h;
    float id = invdeg[node];
    ushort2 sv = h2[(size_t)node * 64 + lane];
    float2 acc = make_float2(bf2f(sv.x) * id, bf2f(sv.y) * id);
    int e0 = rowptr[node], e1 = rowptr[node + 1];
    int e = e0;
    for (; e + 1 < e1; e += 2) {
        int2 ed0 = edge2[e], ed1 = edge2[e + 1];
        float w0 = __int_as_float(ed0.y), w1 = __int_as_float(ed1.y);
        ushort2 v0 = h2[(size_t)ed0.x * 64 + lane];
        ushort2 v1 = h2[(size_t)ed1.x * 64 + lane];
        acc.x += bf2f(v0.x) * w0; acc.y += bf2f(v0.y) * w0;
        acc.x += bf2f(v1.x) * w1; acc.y += bf2f(v1.y) * w1;
    }
    if (e < e1) {
        int2 ed0 = edge2[e];
        float w0 = __int_as_float(ed0.y);
        ushort2 v0 = h2[(size_t)ed0.x * 64 + lane];
        acc.x += bf2f(v0.x) * w0; acc.y += bf2f(v0.y) * w0;
    }
    float2 bb = ((const float2*)bias)[lane];
    acc.x += bb.x; acc.y += bb.y;
    ((float2*)out)[(size_t)node * 64 + lane] = acc;
}

// ---------------------------------------------------------------------------
// Global mean pool over sorted batch: 32-node chunks (1563 blocks) for
// latency hiding; run-length accumulate, flush one atomic per boundary.
// ---------------------------------------------------------------------------
__global__ __launch_bounds__(128) void pool_kernel(const float* __restrict__ h,
                                                   const int* __restrict__ batch,
                                                   float* __restrict__ pool,
                                                   float* __restrict__ gcnt) {
    int c = threadIdx.x;
    int n0 = blockIdx.x * POOL_CHUNK;
    int n1 = n0 + POOL_CHUNK;
    if (n1 > N_NODES) n1 = N_NODES;
    if (n0 >= N_NODES) return;
    float run = 0.f, cnt = 0.f;
    int g = batch[n0];
    for (int n = n0; n < n1; n++) {
        int gn = batch[n];
        if (gn != g) {
            atomicAdd(&pool[g * OUT_CH + c], run);
            if (c == 0) atomicAdd(&gcnt[g], cnt);
            run = 0.f; cnt = 0.f; g = gn;
        }
        run += h[(size_t)n * OUT_CH + c];
        if (c == 0) cnt += 1.f;
    }
    atomicAdd(&pool[g * OUT_CH + c], run);
    if (c == 0) atomicAdd(&gcnt[g], cnt);
}

__global__ __launch_bounds__(256) void final_kernel(const float* __restrict__ pool,
                                                    const float* __restrict__ gcnt,
                                                    float* __restrict__ out) {
    int i = blockIdx.x * 256 + threadIdx.x;
    if (i < N_GRAPHS * OUT_CH)
        out[i] = pool[i] / fmaxf(gcnt[i >> 7], 1.0f);
}

// ---------------------------------------------------------------------------
extern "C" void kernel_launch(void* const* d_in, const int* in_sizes, int n_in,
                              void* d_out, int out_size, void* d_ws, size_t ws_size,
                              hipStream_t stream) {
    const float* x  = (const float*)d_in[0];
    const float* W1 = (const float*)d_in[1];
    const float* b1 = (const float*)d_in[2];
    const float* W2 = (const float*)d_in[3];
    const float* b2 = (const float*)d_in[4];
    const int*   ei = (const int*)d_in[5];
    const int*   batch = (const int*)d_in[6];
    float* out = (float*)d_out;

    // workspace layout (16B-aligned by construction)
    unsigned short* xb  = (unsigned short*)d_ws;                 // M_PAD*256 bf16
    unsigned short* h1b = xb  + (size_t)M_PAD * HID;             // M_PAD*256 bf16
    unsigned short* hBb = h1b + (size_t)M_PAD * HID;             // M_PAD*256 bf16
    unsigned short* h2b = hBb + (size_t)M_PAD * HID;             // M_PAD*128 bf16
    unsigned short* w1t = h2b + (size_t)M_PAD * OUT_CH;          // 256*256
    unsigned short* w2t = w1t + HID * IN_CH;                     // 128*256
    float* hC  = (float*)xb;   // agg2 f32 out aliases xb (xb dead after gemm1)
    float* dinv   = (float*)(w2t + OUT_CH * HID);                // 50000
    float* invdeg = dinv + N_NODES;                              // 50000
    int*   rowptr = (int*)(invdeg + N_NODES);                    // 50001 (pad 50016)
    int2*  edge2  = (int2*)(rowptr + 50016);                     // 800000 int2
    int*   cnt    = (int*)(edge2 + N_EDGES);                     // 50000 } zeroed
    int*   fillp  = cnt + N_NODES;                               // 50000 } zeroed
    float* gcnt   = (float*)(fillp + N_NODES);                   // 64    } zeroed
    float* pool   = gcnt + N_GRAPHS;                             // 8192  } zeroed
    int*   blocksum = (int*)(pool + N_GRAPHS * OUT_CH);          // 256
    int*   blockoff = blocksum + 256;                            // 256

    size_t zbytes = ((size_t)N_NODES * 2 + N_GRAPHS + (size_t)N_GRAPHS * OUT_CH) * 4;
    hipMemsetAsync(cnt, 0, zbytes, stream);

    // CSR build
    count_kernel<<<(N_EDGES + 255) / 256, 256, 0, stream>>>(ei, cnt);
    scan_a_kernel<<<SCAN_BLOCKS, 256, 0, stream>>>(cnt, rowptr, blocksum, dinv, invdeg);
    scan_b_kernel<<<1, 256, 0, stream>>>(blocksum, blockoff, rowptr);
    scan_c_kernel<<<SCAN_BLOCKS, 256, 0, stream>>>(rowptr, blockoff);
    fill_kernel<<<(N_EDGES + 255) / 256, 256, 0, stream>>>(ei, rowptr, fillp, edge2, dinv);

    // converts
    cvt_x_kernel<<<(M_PAD * (IN_CH / 4) + 255) / 256, 256, 0, stream>>>(x, xb);
    cvt_w_kernel<<<(HID * IN_CH + OUT_CH * HID + 255) / 256, 256, 0, stream>>>(W1, W2, w1t, w2t);

    // conv1: MFMA gemm -> bf16 h1, aggregate(+ELU) -> bf16 hB
    dim3 g1(M_PAD / 128, HID / 128);
    gemm_mfma_kernel<<<g1, 256, 0, stream>>>(xb, w1t, h1b, HID);
    agg1_kernel<<<(N_NODES + 3) / 4, 256, 0, stream>>>(h1b, b1, rowptr, edge2, invdeg, hBb);

    // conv2: MFMA gemm -> bf16 h2, aggregate -> f32 hC
    dim3 g2(M_PAD / 128, OUT_CH / 128);
    gemm_mfma_kernel<<<g2, 256, 0, stream>>>(hBb, w2t, h2b, OUT_CH);
    agg2_kernel<<<(N_NODES + 3) / 4, 256, 0, stream>>>(h2b, b2, rowptr, edge2, invdeg, hC);

    // mean pool
    pool_kernel<<<POOL_BLOCKS, 128, 0, stream>>>(hC, batch, pool, gcnt);
    final_kernel<<<(N_GRAPHS * OUT_CH + 255) / 256, 256, 0, stream>>>(pool, gcnt, out);
}

// Round 6
// 331.675 us; speedup vs baseline: 2.1096x; 1.0758x over previous
//
#include <hip/hip_runtime.h>
#include <hip/hip_bf16.h>

#define N_NODES 50000
#define N_EDGES 800000
#define IN_CH 256
#define HID 256
#define OUT_CH 128
#define N_GRAPHS 64
#define SCAN_BLOCKS 196   // ceil(50000/256)
#define M_PAD 50048       // 391 * 128
#define POOL_CHUNK 32
#define POOL_BLOCKS ((N_NODES + POOL_CHUNK - 1) / POOL_CHUNK)

typedef __bf16 bf16x8 __attribute__((ext_vector_type(8)));
typedef float f32x4 __attribute__((ext_vector_type(4)));

// bf16 <-> f32 helpers (RNE on pack)
__device__ __forceinline__ float bf2f(unsigned short u) {
    union { unsigned int i; float f; } x; x.i = ((unsigned int)u) << 16; return x.f;
}
__device__ __forceinline__ unsigned short f2bf(float f) {
    union { float f; unsigned int i; } x; x.f = f;
    unsigned int r = x.i + 0x7FFFu + ((x.i >> 16) & 1u);
    return (unsigned short)(r >> 16);
}

__device__ __forceinline__ void load16(const void* g, void* l) {
    __builtin_amdgcn_global_load_lds(
        (const __attribute__((address_space(1))) void*)g,
        (__attribute__((address_space(3))) void*)l, 16, 0, 0);
}

// ---------------------------------------------------------------------------
// CSR build: histogram, 3-phase parallel scan, slot fill (packed int2 edges).
// ---------------------------------------------------------------------------
__global__ __launch_bounds__(256) void count_kernel(const int* __restrict__ ei,
                                                    int* __restrict__ cnt) {
    int e = blockIdx.x * 256 + threadIdx.x;
    if (e < N_EDGES) atomicAdd(&cnt[ei[N_EDGES + e]], 1);
}

__global__ __launch_bounds__(256) void scan_a_kernel(const int* __restrict__ cnt,
                                                     int* __restrict__ rowptr,
                                                     int* __restrict__ blocksum,
                                                     float* __restrict__ dinv,
                                                     float* __restrict__ invdeg) {
    __shared__ int tmp[256];
    int t = threadIdx.x;
    int i = blockIdx.x * 256 + t;
    int v = (i < N_NODES) ? cnt[i] : 0;
    int x = v;
    tmp[t] = x;
    __syncthreads();
#pragma unroll
    for (int off = 1; off < 256; off <<= 1) {
        int y = (t >= off) ? tmp[t - off] : 0;
        __syncthreads();
        x += y;
        tmp[t] = x;
        __syncthreads();
    }
    if (i < N_NODES) {
        rowptr[i] = x - v;
        float d = (float)v + 1.0f;         // +1 self loop
        dinv[i] = rsqrtf(d);
        invdeg[i] = 1.0f / d;
    }
    if (t == 255) blocksum[blockIdx.x] = x;
}

__global__ __launch_bounds__(256) void scan_b_kernel(const int* __restrict__ blocksum,
                                                     int* __restrict__ blockoff,
                                                     int* __restrict__ rowptr) {
    __shared__ int tmp[256];
    int t = threadIdx.x;
    int v = (t < SCAN_BLOCKS) ? blocksum[t] : 0;
    int x = v;
    tmp[t] = x;
    __syncthreads();
#pragma unroll
    for (int off = 1; off < 256; off <<= 1) {
        int y = (t >= off) ? tmp[t - off] : 0;
        __syncthreads();
        x += y;
        tmp[t] = x;
        __syncthreads();
    }
    if (t < SCAN_BLOCKS) blockoff[t] = x - v;
    if (t == 255) rowptr[N_NODES] = x;
}

__global__ __launch_bounds__(256) void scan_c_kernel(int* __restrict__ rowptr,
                                                     const int* __restrict__ blockoff) {
    int i = blockIdx.x * 256 + threadIdx.x;
    if (i < N_NODES) rowptr[i] += blockoff[blockIdx.x];
}

__global__ __launch_bounds__(256) void fill_kernel(const int* __restrict__ ei,
                                                   const int* __restrict__ rowptr,
                                                   int* __restrict__ fillp,
                                                   int2* __restrict__ edge2,
                                                   const float* __restrict__ dinv) {
    int e = blockIdx.x * 256 + threadIdx.x;
    if (e >= N_EDGES) return;
    int s = ei[e];
    int d = ei[N_EDGES + e];
    int p = rowptr[d] + atomicAdd(&fillp[d], 1);
    float w = dinv[s] * dinv[d];
    edge2[p] = make_int2(s, __float_as_int(w));
}

// ---------------------------------------------------------------------------
// Converts: x f32 -> bf16 padded; W1/W2 f32 -> bf16 transposed [N][K].
// ---------------------------------------------------------------------------
__global__ __launch_bounds__(256) void cvt_x_kernel(const float* __restrict__ x,
                                                    unsigned short* __restrict__ xb) {
    int i = blockIdx.x * 256 + threadIdx.x;          // float4 index
    if (i >= M_PAD * (IN_CH / 4)) return;
    ushort4 o;
    if (i < N_NODES * (IN_CH / 4)) {
        float4 v = ((const float4*)x)[i];
        o.x = f2bf(v.x); o.y = f2bf(v.y); o.z = f2bf(v.z); o.w = f2bf(v.w);
    } else {
        o = make_ushort4(0, 0, 0, 0);
    }
    ((ushort4*)xb)[i] = o;
}

__global__ __launch_bounds__(256) void cvt_w_kernel(const float* __restrict__ W1,
                                                    const float* __restrict__ W2,
                                                    unsigned short* __restrict__ w1t,
                                                    unsigned short* __restrict__ w2t) {
    int i = blockIdx.x * 256 + threadIdx.x;
    if (i < HID * IN_CH) {                            // W1t[n][k] = W1[k][n]
        int n = i >> 8, k = i & 255;
        w1t[i] = f2bf(W1[k * HID + n]);
    } else if (i < HID * IN_CH + OUT_CH * HID) {      // W2t[n][k] = W2[k][n]
        int j = i - HID * IN_CH;
        int n = j >> 8, k = j & 255;
        w2t[j] = f2bf(W2[k * OUT_CH + n]);
    }
}

// ---------------------------------------------------------------------------
// bf16 MFMA GEMM: C[M_PAD][N] = A[M_PAD][256] @ Bt[N][256]^T, all bf16.
// 128x128 tile, 4 waves 2x2, each 64x64 = 4x4 mfma_f32_16x16x32_bf16.
// ---------------------------------------------------------------------------
__global__ __launch_bounds__(256) void gemm_mfma_kernel(
        const unsigned short* __restrict__ A,
        const unsigned short* __restrict__ Bt,
        unsigned short* __restrict__ C,
        int N) {
    const int K = 256;
    __shared__ char As[8192];   // [128 rows][32 bf16], 16B chunks XOR-swizzled
    __shared__ char Bs[8192];
    int tid = threadIdx.x;
    int bm = blockIdx.x * 128;
    int bn = blockIdx.y * 128;
    int lane = tid & 63, wave = tid >> 6;
    int lane15 = lane & 15, quad = lane >> 4;
    int wm0 = (wave >> 1) << 6;
    int wn0 = (wave & 1) << 6;

    int s1 = tid, s2 = tid + 256;
    int r1 = s1 >> 2, q1 = (s1 & 3) ^ ((r1 >> 1) & 3);
    int r2 = s2 >> 2, q2 = (s2 & 3) ^ ((r2 >> 1) & 3);
    const char* gA1 = (const char*)(A + (size_t)(bm + r1) * K) + (q1 << 4);
    const char* gA2 = (const char*)(A + (size_t)(bm + r2) * K) + (q2 << 4);
    const char* gB1 = (const char*)(Bt + (size_t)(bn + r1) * K) + (q1 << 4);
    const char* gB2 = (const char*)(Bt + (size_t)(bn + r2) * K) + (q2 << 4);
    char* lA1 = As + (wave << 10);
    char* lA2 = As + 4096 + (wave << 10);
    char* lB1 = Bs + (wave << 10);
    char* lB2 = Bs + 4096 + (wave << 10);

    int swm = (lane15 >> 1) & 3;
    f32x4 acc[4][4];
#pragma unroll
    for (int mt = 0; mt < 4; mt++)
#pragma unroll
        for (int nt = 0; nt < 4; nt++)
            acc[mt][nt] = (f32x4){0.f, 0.f, 0.f, 0.f};

    for (int k0 = 0; k0 < K; k0 += 32) {
        __syncthreads();
        load16(gA1 + (k0 << 1), lA1);
        load16(gA2 + (k0 << 1), lA2);
        load16(gB1 + (k0 << 1), lB1);
        load16(gB2 + (k0 << 1), lB2);
        __syncthreads();
        bf16x8 af[4], bfr[4];
#pragma unroll
        for (int t = 0; t < 4; t++) {
            int ra = wm0 + t * 16 + lane15;
            af[t] = *(const bf16x8*)(As + ra * 64 + ((quad ^ swm) << 4));
            int rb = wn0 + t * 16 + lane15;
            bfr[t] = *(const bf16x8*)(Bs + rb * 64 + ((quad ^ swm) << 4));
        }
#pragma unroll
        for (int mt = 0; mt < 4; mt++)
#pragma unroll
            for (int nt = 0; nt < 4; nt++)
                acc[mt][nt] = __builtin_amdgcn_mfma_f32_16x16x32_bf16(
                    af[mt], bfr[nt], acc[mt][nt], 0, 0, 0);
    }

#pragma unroll
    for (int mt = 0; mt < 4; mt++) {
        int rowb = bm + wm0 + mt * 16 + quad * 4;
#pragma unroll
        for (int nt = 0; nt < 4; nt++) {
            int col = bn + wn0 + nt * 16 + lane15;
            f32x4 a = acc[mt][nt];
            C[(size_t)(rowb + 0) * N + col] = f2bf(a[0]);
            C[(size_t)(rowb + 1) * N + col] = f2bf(a[1]);
            C[(size_t)(rowb + 2) * N + col] = f2bf(a[2]);
            C[(size_t)(rowb + 3) * N + col] = f2bf(a[3]);
        }
    }
}

// ---------------------------------------------------------------------------
// GCN aggregation, 256ch (conv1): wave/node, lane = 4ch, bf16 gathers,
// 4-edge unroll (4 gathers in flight), f32 accumulate, ELU, bf16 output.
// ---------------------------------------------------------------------------
__global__ __launch_bounds__(256) void agg1_kernel(const unsigned short* __restrict__ h,
                                                   const float* __restrict__ bias,
                                                   const int* __restrict__ rowptr,
                                                   const int2* __restrict__ edge2,
                                                   const float* __restrict__ invdeg,
                                                   unsigned short* __restrict__ out) {
    int node = blockIdx.x * 4 + (threadIdx.x >> 6);
    if (node >= N_NODES) return;
    int lane = threadIdx.x & 63;
    const ushort4* h4 = (const ushort4*)h;
    float id = invdeg[node];
    ushort4 sv = h4[(size_t)node * 64 + lane];
    float4 acc = make_float4(bf2f(sv.x) * id, bf2f(sv.y) * id,
                             bf2f(sv.z) * id, bf2f(sv.w) * id);
    int e0 = rowptr[node], e1 = rowptr[node + 1];
    int e = e0;
    for (; e + 3 < e1; e += 4) {
        int2 ed0 = edge2[e],     ed1 = edge2[e + 1];
        int2 ed2 = edge2[e + 2], ed3 = edge2[e + 3];
        ushort4 v0 = h4[(size_t)ed0.x * 64 + lane];
        ushort4 v1 = h4[(size_t)ed1.x * 64 + lane];
        ushort4 v2 = h4[(size_t)ed2.x * 64 + lane];
        ushort4 v3 = h4[(size_t)ed3.x * 64 + lane];
        float w0 = __int_as_float(ed0.y), w1 = __int_as_float(ed1.y);
        float w2 = __int_as_float(ed2.y), w3 = __int_as_float(ed3.y);
        acc.x += bf2f(v0.x) * w0; acc.y += bf2f(v0.y) * w0;
        acc.z += bf2f(v0.z) * w0; acc.w += bf2f(v0.w) * w0;
        acc.x += bf2f(v1.x) * w1; acc.y += bf2f(v1.y) * w1;
        acc.z += bf2f(v1.z) * w1; acc.w += bf2f(v1.w) * w1;
        acc.x += bf2f(v2.x) * w2; acc.y += bf2f(v2.y) * w2;
        acc.z += bf2f(v2.z) * w2; acc.w += bf2f(v2.w) * w2;
        acc.x += bf2f(v3.x) * w3; acc.y += bf2f(v3.y) * w3;
        acc.z += bf2f(v3.z) * w3; acc.w += bf2f(v3.w) * w3;
    }
    for (; e < e1; e++) {
        int2 ed0 = edge2[e];
        float w0 = __int_as_float(ed0.y);
        ushort4 v0 = h4[(size_t)ed0.x * 64 + lane];
        acc.x += bf2f(v0.x) * w0; acc.y += bf2f(v0.y) * w0;
        acc.z += bf2f(v0.z) * w0; acc.w += bf2f(v0.w) * w0;
    }
    float4 bb = ((const float4*)bias)[lane];
    acc.x += bb.x; acc.y += bb.y; acc.z += bb.z; acc.w += bb.w;
    acc.x = acc.x > 0.f ? acc.x : expm1f(acc.x);
    acc.y = acc.y > 0.f ? acc.y : expm1f(acc.y);
    acc.z = acc.z > 0.f ? acc.z : expm1f(acc.z);
    acc.w = acc.w > 0.f ? acc.w : expm1f(acc.w);
    ushort4 o;
    o.x = f2bf(acc.x); o.y = f2bf(acc.y); o.z = f2bf(acc.z); o.w = f2bf(acc.w);
    ((ushort4*)out)[(size_t)node * 64 + lane] = o;
}

// 128ch (conv2): wave/node, lane = 2ch, 4-edge unroll, f32 output.
__global__ __launch_bounds__(256) void agg2_kernel(const unsigned short* __restrict__ h,
                                                   const float* __restrict__ bias,
                                                   const int* __restrict__ rowptr,
                                                   const int2* __restrict__ edge2,
                                                   const float* __restrict__ invdeg,
                                                   float* __restrict__ out) {
    int node = blockIdx.x * 4 + (threadIdx.x >> 6);
    if (node >= N_NODES) return;
    int lane = threadIdx.x & 63;
    const ushort2* h2 = (const ushort2*)h;
    float id = invdeg[node];
    ushort2 sv = h2[(size_t)node * 64 + lane];
    float2 acc = make_float2(bf2f(sv.x) * id, bf2f(sv.y) * id);
    int e0 = rowptr[node], e1 = rowptr[node + 1];
    int e = e0;
    for (; e + 3 < e1; e += 4) {
        int2 ed0 = edge2[e],     ed1 = edge2[e + 1];
        int2 ed2 = edge2[e + 2], ed3 = edge2[e + 3];
        ushort2 v0 = h2[(size_t)ed0.x * 64 + lane];
        ushort2 v1 = h2[(size_t)ed1.x * 64 + lane];
        ushort2 v2 = h2[(size_t)ed2.x * 64 + lane];
        ushort2 v3 = h2[(size_t)ed3.x * 64 + lane];
        float w0 = __int_as_float(ed0.y), w1 = __int_as_float(ed1.y);
        float w2 = __int_as_float(ed2.y), w3 = __int_as_float(ed3.y);
        acc.x += bf2f(v0.x) * w0; acc.y += bf2f(v0.y) * w0;
        acc.x += bf2f(v1.x) * w1; acc.y += bf2f(v1.y) * w1;
        acc.x += bf2f(v2.x) * w2; acc.y += bf2f(v2.y) * w2;
        acc.x += bf2f(v3.x) * w3; acc.y += bf2f(v3.y) * w3;
    }
    for (; e < e1; e++) {
        int2 ed0 = edge2[e];
        float w0 = __int_as_float(ed0.y);
        ushort2 v0 = h2[(size_t)ed0.x * 64 + lane];
        acc.x += bf2f(v0.x) * w0; acc.y += bf2f(v0.y) * w0;
    }
    float2 bb = ((const float2*)bias)[lane];
    acc.x += bb.x; acc.y += bb.y;
    ((float2*)out)[(size_t)node * 64 + lane] = acc;
}

// ---------------------------------------------------------------------------
// Global mean pool over sorted batch: 32-node chunks for latency hiding.
// ---------------------------------------------------------------------------
__global__ __launch_bounds__(128) void pool_kernel(const float* __restrict__ h,
                                                   const int* __restrict__ batch,
                                                   float* __restrict__ pool,
                                                   float* __restrict__ gcnt) {
    int c = threadIdx.x;
    int n0 = blockIdx.x * POOL_CHUNK;
    int n1 = n0 + POOL_CHUNK;
    if (n1 > N_NODES) n1 = N_NODES;
    if (n0 >= N_NODES) return;
    float run = 0.f, cnt = 0.f;
    int g = batch[n0];
    for (int n = n0; n < n1; n++) {
        int gn = batch[n];
        if (gn != g) {
            atomicAdd(&pool[g * OUT_CH + c], run);
            if (c == 0) atomicAdd(&gcnt[g], cnt);
            run = 0.f; cnt = 0.f; g = gn;
        }
        run += h[(size_t)n * OUT_CH + c];
        if (c == 0) cnt += 1.f;
    }
    atomicAdd(&pool[g * OUT_CH + c], run);
    if (c == 0) atomicAdd(&gcnt[g], cnt);
}

__global__ __launch_bounds__(256) void final_kernel(const float* __restrict__ pool,
                                                    const float* __restrict__ gcnt,
                                                    float* __restrict__ out) {
    int i = blockIdx.x * 256 + threadIdx.x;
    if (i < N_GRAPHS * OUT_CH)
        out[i] = pool[i] / fmaxf(gcnt[i >> 7], 1.0f);
}

// ---------------------------------------------------------------------------
extern "C" void kernel_launch(void* const* d_in, const int* in_sizes, int n_in,
                              void* d_out, int out_size, void* d_ws, size_t ws_size,
                              hipStream_t stream) {
    const float* x  = (const float*)d_in[0];
    const float* W1 = (const float*)d_in[1];
    const float* b1 = (const float*)d_in[2];
    const float* W2 = (const float*)d_in[3];
    const float* b2 = (const float*)d_in[4];
    const int*   ei = (const int*)d_in[5];
    const int*   batch = (const int*)d_in[6];
    float* out = (float*)d_out;

    // workspace layout (16B-aligned by construction)
    unsigned short* xb  = (unsigned short*)d_ws;                 // M_PAD*256 bf16
    unsigned short* h1b = xb  + (size_t)M_PAD * HID;             // M_PAD*256 bf16
    unsigned short* hBb = h1b + (size_t)M_PAD * HID;             // M_PAD*256 bf16
    unsigned short* h2b = hBb + (size_t)M_PAD * HID;             // M_PAD*128 bf16
    unsigned short* w1t = h2b + (size_t)M_PAD * OUT_CH;          // 256*256
    unsigned short* w2t = w1t + HID * IN_CH;                     // 128*256
    float* hC  = (float*)xb;   // agg2 f32 out aliases xb (xb dead after gemm1)
    float* dinv   = (float*)(w2t + OUT_CH * HID);                // 50000
    float* invdeg = dinv + N_NODES;                              // 50000
    int*   rowptr = (int*)(invdeg + N_NODES);                    // 50001 (pad 50016)
    int2*  edge2  = (int2*)(rowptr + 50016);                     // 800000 int2
    int*   cnt    = (int*)(edge2 + N_EDGES);                     // 50000 } zeroed
    int*   fillp  = cnt + N_NODES;                               // 50000 } zeroed
    float* gcnt   = (float*)(fillp + N_NODES);                   // 64    } zeroed
    float* pool   = gcnt + N_GRAPHS;                             // 8192  } zeroed
    int*   blocksum = (int*)(pool + N_GRAPHS * OUT_CH);          // 256
    int*   blockoff = blocksum + 256;                            // 256

    size_t zbytes = ((size_t)N_NODES * 2 + N_GRAPHS + (size_t)N_GRAPHS * OUT_CH) * 4;
    hipMemsetAsync(cnt, 0, zbytes, stream);

    // CSR build
    count_kernel<<<(N_EDGES + 255) / 256, 256, 0, stream>>>(ei, cnt);
    scan_a_kernel<<<SCAN_BLOCKS, 256, 0, stream>>>(cnt, rowptr, blocksum, dinv, invdeg);
    scan_b_kernel<<<1, 256, 0, stream>>>(blocksum, blockoff, rowptr);
    scan_c_kernel<<<SCAN_BLOCKS, 256, 0, stream>>>(rowptr, blockoff);
    fill_kernel<<<(N_EDGES + 255) / 256, 256, 0, stream>>>(ei, rowptr, fillp, edge2, dinv);

    // converts
    cvt_x_kernel<<<(M_PAD * (IN_CH / 4) + 255) / 256, 256, 0, stream>>>(x, xb);
    cvt_w_kernel<<<(HID * IN_CH + OUT_CH * HID + 255) / 256, 256, 0, stream>>>(W1, W2, w1t, w2t);

    // conv1: MFMA gemm -> bf16 h1, aggregate(+ELU) -> bf16 hB
    dim3 g1(M_PAD / 128, HID / 128);
    gemm_mfma_kernel<<<g1, 256, 0, stream>>>(xb, w1t, h1b, HID);
    agg1_kernel<<<(N_NODES + 3) / 4, 256, 0, stream>>>(h1b, b1, rowptr, edge2, invdeg, hBb);

    // conv2: MFMA gemm -> bf16 h2, aggregate -> f32 hC
    dim3 g2(M_PAD / 128, OUT_CH / 128);
    gemm_mfma_kernel<<<g2, 256, 0, stream>>>(hBb, w2t, h2b, OUT_CH);
    agg2_kernel<<<(N_NODES + 3) / 4, 256, 0, stream>>>(h2b, b2, rowptr, edge2, invdeg, hC);

    // mean pool
    pool_kernel<<<POOL_BLOCKS, 128, 0, stream>>>(hC, batch, pool, gcnt);
    final_kernel<<<(N_GRAPHS * OUT_CH + 255) / 256, 256, 0, stream>>>(pool, gcnt, out);
}